// Round 3
// baseline (892.925 us; speedup 1.0000x reference)
//
#include <hip/hip_runtime.h>

#define DIM 64
#define DEA 32

// ---------------------------------------------------------------------------
// Node linear: q = x@Wq+bq, kv = interleaved [k|v], agg = x@Ws+bs
// ---------------------------------------------------------------------------
__global__ __launch_bounds__(256) void node_lin_kernel(
    const float* __restrict__ x,
    const float* __restrict__ wq, const float* __restrict__ bq,
    const float* __restrict__ wk, const float* __restrict__ bk,
    const float* __restrict__ wv, const float* __restrict__ bv,
    const float* __restrict__ wsk, const float* __restrict__ bsk,
    float* __restrict__ q, float* __restrict__ kv,
    float* __restrict__ agg, int n_nodes)
{
    __shared__ float lw[4][DIM * DIM];   // 64 KB
    __shared__ float lx[16][DIM];        // 4 KB
    const int tid = threadIdx.x;

    {
        const float* srcs[4] = {wq, wk, wv, wsk};
        #pragma unroll
        for (int m = 0; m < 4; ++m) {
            const float4* s4 = (const float4*)srcs[m];
            float4* d4 = (float4*)lw[m];
            #pragma unroll
            for (int i = 0; i < 4; ++i) d4[tid + i * 256] = s4[tid + i * 256];
        }
    }
    const int base = blockIdx.x * 16;
    {
        const int r = tid >> 4;
        const int c = (tid & 15) * 4;
        const int n = base + r;
        float4 val = make_float4(0.f, 0.f, 0.f, 0.f);
        if (n < n_nodes) val = *(const float4*)&x[(size_t)n * DIM + c];
        *(float4*)&lx[r][c] = val;
    }
    __syncthreads();

    const int oc = tid & 63;
    const int nl = tid >> 6;
    float aq[4] = {0, 0, 0, 0}, ak[4] = {0, 0, 0, 0};
    float av[4] = {0, 0, 0, 0}, as_[4] = {0, 0, 0, 0};
    #pragma unroll 8
    for (int kk = 0; kk < DIM; ++kk) {
        const float wqv = lw[0][kk * DIM + oc];
        const float wkv = lw[1][kk * DIM + oc];
        const float wvv = lw[2][kk * DIM + oc];
        const float wsv = lw[3][kk * DIM + oc];
        #pragma unroll
        for (int r = 0; r < 4; ++r) {
            const float xv = lx[nl * 4 + r][kk];
            aq[r]  = fmaf(xv, wqv, aq[r]);
            ak[r]  = fmaf(xv, wkv, ak[r]);
            av[r]  = fmaf(xv, wvv, av[r]);
            as_[r] = fmaf(xv, wsv, as_[r]);
        }
    }
    const float bqv = bq[oc], bkv = bk[oc], bvv = bv[oc], bsv = bsk[oc];
    #pragma unroll
    for (int r = 0; r < 4; ++r) {
        const int n = base + nl * 4 + r;
        if (n < n_nodes) {
            q[(size_t)n * DIM + oc]          = aq[r] + bqv;
            kv[(size_t)n * 128 + oc]         = ak[r] + bkv;
            kv[(size_t)n * 128 + 64 + oc]    = av[r] + bvv;
            agg[(size_t)n * DIM + oc]        = as_[r] + bsv;   // root skip
        }
    }
}

// ---------------------------------------------------------------------------
// CSR build over dst: histogram -> exclusive scan -> scatter
// ---------------------------------------------------------------------------
__global__ __launch_bounds__(256) void hist_kernel(
    const int* __restrict__ dst, int* __restrict__ counts, int n_edges, int n_nodes)
{
    const int eid = blockIdx.x * 256 + threadIdx.x;
    if (eid >= n_edges) return;
    int d = dst[eid];
    d = (d < 0) ? 0 : ((d >= n_nodes) ? n_nodes - 1 : d);
    atomicAdd(&counts[d], 1);
}

__global__ __launch_bounds__(1024) void scan_kernel(
    int* __restrict__ counts_cursor, int* __restrict__ row_ptr, int n)
{
    __shared__ int ls[1024];
    __shared__ int carry;
    const int tid = threadIdx.x;
    if (tid == 0) carry = 0;
    __syncthreads();
    for (int base = 0; base < n; base += 1024) {
        const int idx = base + tid;
        const int val = (idx < n) ? counts_cursor[idx] : 0;
        ls[tid] = val;
        __syncthreads();
        for (int off = 1; off < 1024; off <<= 1) {
            int t = (tid >= off) ? ls[tid - off] : 0;
            __syncthreads();
            if (tid >= off) ls[tid] += t;
            __syncthreads();
        }
        const int excl = ls[tid] - val + carry;
        if (idx < n) { row_ptr[idx] = excl; counts_cursor[idx] = excl; }
        __syncthreads();
        if (tid == 0) carry += ls[1023];
        __syncthreads();
    }
    if (tid == 0) row_ptr[n] = carry;
}

__global__ __launch_bounds__(256) void scatter_kernel(
    const int* __restrict__ dst, int* __restrict__ cursor,
    int* __restrict__ perm, int n_edges, int n_nodes)
{
    const int eid = blockIdx.x * 256 + threadIdx.x;
    if (eid >= n_edges) return;
    int d = dst[eid];
    d = (d < 0) ? 0 : ((d >= n_nodes) ? n_nodes - 1 : d);
    const int pos = atomicAdd(&cursor[d], 1);
    perm[pos] = eid;
}

// ---------------------------------------------------------------------------
// Reorder: src_perm[i] = clamp(src[perm[i]]); optionally ea_perm[i] = ea[perm[i]]
// 8 lanes per edge (comp = tid&7 copies one float4 of the 128B ea row).
// ---------------------------------------------------------------------------
__global__ __launch_bounds__(256) void reorder_kernel(
    const int* __restrict__ perm, const int* __restrict__ src,
    const float* __restrict__ ea, int* __restrict__ src_perm,
    float* __restrict__ ea_perm, int n_edges, int n_nodes)
{
    const int t = blockIdx.x * 256 + threadIdx.x;
    const int i = t >> 3;
    const int comp = t & 7;
    if (i >= n_edges) return;
    const int eid = perm[i];
    if (comp == 0) {
        int s = src[eid];
        s = (s < 0) ? 0 : ((s >= n_nodes) ? n_nodes - 1 : s);
        src_perm[i] = s;
    }
    if (ea_perm) {
        *(float4*)&ea_perm[(size_t)i * DEA + comp * 4] =
            *(const float4*)&ea[(size_t)eid * DEA + comp * 4];
    }
}

// ---------------------------------------------------------------------------
// Fused aggregation v2: one wave per dst node; 4 edge-groups x 16 lanes;
// lane holds 4 channels. Online softmax per group, 2-step shfl merge.
// ---------------------------------------------------------------------------
__global__ __launch_bounds__(256) void fused_edge_kernel(
    const float* __restrict__ q, const float* __restrict__ kv,
    const float* __restrict__ ea_src, const float* __restrict__ we,
    const float* __restrict__ aggskip,
    const int* __restrict__ row_ptr, const int* __restrict__ src_perm,
    const int* __restrict__ perm,     // non-null => ea indexed via perm[i]
    float* __restrict__ h_out, int n_nodes)
{
    __shared__ float lw[DEA * DIM];   // 8 KB
    const int tid = threadIdx.x;
    {
        const float4* s4 = (const float4*)we;
        float4* d4 = (float4*)lw;
        d4[tid] = s4[tid];
        d4[tid + 256] = s4[tid + 256];
    }
    __syncthreads();

    const int wave = tid >> 6;
    const int lane = tid & 63;
    const int g = lane >> 4;
    const int j = lane & 15;
    const int node = blockIdx.x * 4 + wave;
    if (node >= n_nodes) return;

    const float4 q4 = *(const float4*)&q[(size_t)node * DIM + j * 4];
    const int beg = row_ptr[node], end = row_ptr[node + 1];
    const float4* lw4 = (const float4*)lw;

    float m = -3.0e38f, l = 0.f;
    float4 msg = make_float4(0.f, 0.f, 0.f, 0.f);

    for (int i0 = beg; i0 < end; i0 += 4) {
        const int i = i0 + g;
        const bool act = (i < end);
        const int ii = act ? i : i0;

        const int s = src_perm[ii];                       // broadcast in group
        const float4* kvp = (const float4*)&kv[(size_t)s * 128];

        const float4* er;
        if (perm) er = (const float4*)&ea_src[(size_t)perm[ii] * DEA];
        else      er = (const float4*)&ea_src[(size_t)ii * DEA];

        // issue gathers early; e-compute below hides their latency
        const float4 k4 = kvp[j];
        const float4 v4 = kvp[16 + j];

        // e = ea_row @ We for this lane's 4 channels
        float4 e4 = make_float4(0.f, 0.f, 0.f, 0.f);
        #pragma unroll
        for (int jj = 0; jj < 8; ++jj) {
            const float4 a4 = er[jj];
            const float4 w0 = lw4[(jj * 4 + 0) * 16 + j];
            const float4 w1 = lw4[(jj * 4 + 1) * 16 + j];
            const float4 w2 = lw4[(jj * 4 + 2) * 16 + j];
            const float4 w3 = lw4[(jj * 4 + 3) * 16 + j];
            e4.x = fmaf(a4.x, w0.x, fmaf(a4.y, w1.x, fmaf(a4.z, w2.x, fmaf(a4.w, w3.x, e4.x))));
            e4.y = fmaf(a4.x, w0.y, fmaf(a4.y, w1.y, fmaf(a4.z, w2.y, fmaf(a4.w, w3.y, e4.y))));
            e4.z = fmaf(a4.x, w0.z, fmaf(a4.y, w1.z, fmaf(a4.z, w2.z, fmaf(a4.w, w3.z, e4.z))));
            e4.w = fmaf(a4.x, w0.w, fmaf(a4.y, w1.w, fmaf(a4.z, w2.w, fmaf(a4.w, w3.w, e4.w))));
        }

        // score = q . (k + e) reduced over the 16-lane group
        float t = q4.x * (k4.x + e4.x);
        t = fmaf(q4.y, k4.y + e4.y, t);
        t = fmaf(q4.z, k4.z + e4.z, t);
        t = fmaf(q4.w, k4.w + e4.w, t);
        t += __shfl_xor(t, 1, 64);
        t += __shfl_xor(t, 2, 64);
        t += __shfl_xor(t, 4, 64);
        t += __shfl_xor(t, 8, 64);
        const float score = act ? t * 0.125f : -3.0e38f;

        const float mn = fmaxf(m, score);
        const float p  = act ? __expf(score - mn) : 0.f;
        const float sc = __expf(m - mn);
        l = l * sc + p;
        msg.x = fmaf(p, v4.x + e4.x, msg.x * sc);
        msg.y = fmaf(p, v4.y + e4.y, msg.y * sc);
        msg.z = fmaf(p, v4.z + e4.z, msg.z * sc);
        msg.w = fmaf(p, v4.w + e4.w, msg.w * sc);
        m = mn;
    }

    // merge the 4 groups (xor 16, then 32)
    #pragma unroll
    for (int off = 16; off <= 32; off <<= 1) {
        const float m2 = __shfl_xor(m, off, 64);
        const float l2 = __shfl_xor(l, off, 64);
        float4 msg2;
        msg2.x = __shfl_xor(msg.x, off, 64);
        msg2.y = __shfl_xor(msg.y, off, 64);
        msg2.z = __shfl_xor(msg.z, off, 64);
        msg2.w = __shfl_xor(msg.w, off, 64);
        const float mn = fmaxf(m, m2);
        const float s1 = __expf(m - mn);
        const float s2 = __expf(m2 - mn);
        l = l * s1 + l2 * s2;
        msg.x = msg.x * s1 + msg2.x * s2;
        msg.y = msg.y * s1 + msg2.y * s2;
        msg.z = msg.z * s1 + msg2.z * s2;
        msg.w = msg.w * s1 + msg2.w * s2;
        m = mn;
    }

    if (lane < 16) {
        const float inv = (l > 0.f) ? (1.f / l) : 0.f;
        const float4 sk = *(const float4*)&aggskip[(size_t)node * DIM + j * 4];
        float4 o;
        o.x = fmaxf(fmaf(msg.x, inv, sk.x), 0.f);
        o.y = fmaxf(fmaf(msg.y, inv, sk.y), 0.f);
        o.z = fmaxf(fmaf(msg.z, inv, sk.z), 0.f);
        o.w = fmaxf(fmaf(msg.w, inv, sk.w), 0.f);
        *(float4*)&h_out[(size_t)node * DIM + j * 4] = o;
    }
}

// ---------------------------------------------------------------------------
// Final: out = relu(concat(h1,h2) @ skip_w + skip_b), K=128
// ---------------------------------------------------------------------------
__global__ __launch_bounds__(256) void final_kernel(
    const float* __restrict__ h1, const float* __restrict__ h2,
    const float* __restrict__ w, const float* __restrict__ b,
    float* __restrict__ out, int n_nodes)
{
    __shared__ float lw[128 * DIM];   // 32 KB
    __shared__ float lx[16][128];     // 8 KB
    const int tid = threadIdx.x;
    {
        const float4* s4 = (const float4*)w;
        float4* d4 = (float4*)lw;
        #pragma unroll
        for (int i = 0; i < 8; ++i) d4[tid + i * 256] = s4[tid + i * 256];
    }
    const int base = blockIdx.x * 16;
    {
        #pragma unroll
        for (int t = 0; t < 2; ++t) {
            const int f = tid + t * 256;
            const int r = f >> 5;
            const int cf = f & 31;
            const int n = base + r;
            float4 val = make_float4(0.f, 0.f, 0.f, 0.f);
            if (n < n_nodes) {
                if (cf < 16) val = *(const float4*)&h1[(size_t)n * DIM + cf * 4];
                else         val = *(const float4*)&h2[(size_t)n * DIM + (cf - 16) * 4];
            }
            *(float4*)&lx[r][cf * 4] = val;
        }
    }
    __syncthreads();

    const int oc = tid & 63;
    const int nl = tid >> 6;
    float acc[4] = {0, 0, 0, 0};
    #pragma unroll 8
    for (int kk = 0; kk < 128; ++kk) {
        const float wv = lw[kk * DIM + oc];
        #pragma unroll
        for (int r = 0; r < 4; ++r)
            acc[r] = fmaf(lx[nl * 4 + r][kk], wv, acc[r]);
    }
    const float bv = b[oc];
    #pragma unroll
    for (int r = 0; r < 4; ++r) {
        const int n = base + nl * 4 + r;
        if (n < n_nodes) out[(size_t)n * DIM + oc] = fmaxf(acc[r] + bv, 0.f);
    }
}

// ---------------------------------------------------------------------------
extern "C" void kernel_launch(void* const* d_in, const int* in_sizes, int n_in,
                              void* d_out, int out_size, void* d_ws, size_t ws_size,
                              hipStream_t stream)
{
    const float* x     = (const float*)d_in[0];
    const int*   ei    = (const int*)d_in[1];
    const float* eattr = (const float*)d_in[2];
    const float *q1w = (const float*)d_in[3],  *q1b = (const float*)d_in[4];
    const float *k1w = (const float*)d_in[5],  *k1b = (const float*)d_in[6];
    const float *v1w = (const float*)d_in[7],  *v1b = (const float*)d_in[8];
    const float *e1w = (const float*)d_in[9];
    const float *s1w = (const float*)d_in[10], *s1b = (const float*)d_in[11];
    const float *q2w = (const float*)d_in[12], *q2b = (const float*)d_in[13];
    const float *k2w = (const float*)d_in[14], *k2b = (const float*)d_in[15];
    const float *v2w = (const float*)d_in[16], *v2b = (const float*)d_in[17];
    const float *e2w = (const float*)d_in[18];
    const float *s2w = (const float*)d_in[19], *s2b = (const float*)d_in[20];
    const float *skw = (const float*)d_in[21], *skb = (const float*)d_in[22];

    const int N = in_sizes[0] / DIM;
    const int E = in_sizes[1] / 2;
    const int* src = ei;
    const int* dst = ei + E;

    float* ws = (float*)d_ws;
    const size_t nf = (size_t)N * DIM;
    float* q    = ws;            // nf
    float* kv   = q + nf;        // 2*nf
    float* agg  = kv + 2 * nf;   // nf
    float* h1   = agg + nf;      // nf
    float* h2   = h1 + nf;       // nf
    float* tail = h2 + nf;       // 6*nf so far

    // Path A stores ea in perm order (32E floats); path B reads ea via perm.
    const size_t int_need = 2 * (size_t)N + 1 + 2 * (size_t)E;
    const bool pathA =
        ws_size >= (6 * nf + 32 * (size_t)E) * sizeof(float) + int_need * sizeof(int) + 256;
    float* ea_perm = pathA ? tail : nullptr;
    int* ip = (int*)(pathA ? (tail + 32 * (size_t)E) : tail);
    int* row_ptr  = ip;                 // N+1
    int* cursor   = row_ptr + N + 1;    // N
    int* perm     = cursor + N;         // E
    int* src_perm = perm + E;           // E

    const int nblk = (N + 15) / 16;
    const int eblk = (E + 255) / 256;
    const int rblk = (E * 8 + 255) / 256;
    const int fblk = (N + 3) / 4;

    // ---------------- CSR + reorder (shared by both layers) ----------------
    hipMemsetAsync(cursor, 0, (size_t)N * sizeof(int), stream);
    hist_kernel<<<eblk, 256, 0, stream>>>(dst, cursor, E, N);
    scan_kernel<<<1, 1024, 0, stream>>>(cursor, row_ptr, N);
    scatter_kernel<<<eblk, 256, 0, stream>>>(dst, cursor, perm, E, N);
    reorder_kernel<<<rblk, 256, 0, stream>>>(perm, src, eattr, src_perm, ea_perm, E, N);

    const float* eaA   = pathA ? ea_perm : eattr;
    const int*   permA = pathA ? nullptr : perm;

    // ---------------- layer 1 ----------------
    node_lin_kernel<<<nblk, 256, 0, stream>>>(x, q1w, q1b, k1w, k1b, v1w, v1b,
                                              s1w, s1b, q, kv, agg, N);
    fused_edge_kernel<<<fblk, 256, 0, stream>>>(q, kv, eaA, e1w, agg,
                                                row_ptr, src_perm, permA, h1, N);

    // ---------------- layer 2 ----------------
    node_lin_kernel<<<nblk, 256, 0, stream>>>(h1, q2w, q2b, k2w, k2b, v2w, v2b,
                                              s2w, s2b, q, kv, agg, N);
    fused_edge_kernel<<<fblk, 256, 0, stream>>>(q, kv, eaA, e2w, agg,
                                                row_ptr, src_perm, permA, h2, N);

    // ---------------- final skip MLP ----------------
    final_kernel<<<nblk, 256, 0, stream>>>(h1, h2, skw, skb, (float*)d_out, N);
}

// Round 4
// 542.318 us; speedup vs baseline: 1.6465x; 1.6465x over previous
//
#include <hip/hip_runtime.h>

#define DIM 64
#define DEA 32

// ---------------------------------------------------------------------------
// Node linear: q = x@Wq+bq, kv = interleaved [k|v], agg = x@Ws+bs,
// qwe = q @ We^T  ([N,32], for per-edge score dot against edge_attr).
// ---------------------------------------------------------------------------
__global__ __launch_bounds__(256) void node_lin_kernel(
    const float* __restrict__ x,
    const float* __restrict__ wq, const float* __restrict__ bq,
    const float* __restrict__ wk, const float* __restrict__ bk,
    const float* __restrict__ wv, const float* __restrict__ bv,
    const float* __restrict__ wsk, const float* __restrict__ bsk,
    const float* __restrict__ we,
    float* __restrict__ q, float* __restrict__ kv,
    float* __restrict__ agg, float* __restrict__ qwe, int n_nodes)
{
    __shared__ float lw[4][DIM * DIM];   // 64 KB
    __shared__ float lx[16][DIM];        // 4 KB
    __shared__ float lwe_t[DIM * 33];    // 8.25 KB, We transposed, stride 33
    __shared__ float lq[16][DIM];        // 4 KB
    const int tid = threadIdx.x;

    {
        const float* srcs[4] = {wq, wk, wv, wsk};
        #pragma unroll
        for (int m = 0; m < 4; ++m) {
            const float4* s4 = (const float4*)srcs[m];
            float4* d4 = (float4*)lw[m];
            #pragma unroll
            for (int i = 0; i < 4; ++i) d4[tid + i * 256] = s4[tid + i * 256];
        }
        const float4* we4 = (const float4*)we;   // [32][64] row-major
        #pragma unroll
        for (int t = 0; t < 2; ++t) {
            const int f = tid + t * 256;         // 512 float4
            const int j = f >> 4;
            const int c4 = (f & 15) * 4;
            const float4 w4 = we4[f];
            lwe_t[(c4 + 0) * 33 + j] = w4.x;
            lwe_t[(c4 + 1) * 33 + j] = w4.y;
            lwe_t[(c4 + 2) * 33 + j] = w4.z;
            lwe_t[(c4 + 3) * 33 + j] = w4.w;
        }
    }
    const int base = blockIdx.x * 16;
    {
        const int r = tid >> 4;
        const int c = (tid & 15) * 4;
        const int n = base + r;
        float4 val = make_float4(0.f, 0.f, 0.f, 0.f);
        if (n < n_nodes) val = *(const float4*)&x[(size_t)n * DIM + c];
        *(float4*)&lx[r][c] = val;
    }
    __syncthreads();

    const int oc = tid & 63;
    const int nl = tid >> 6;
    float aq[4] = {0, 0, 0, 0}, ak[4] = {0, 0, 0, 0};
    float av[4] = {0, 0, 0, 0}, as_[4] = {0, 0, 0, 0};
    #pragma unroll 8
    for (int kk = 0; kk < DIM; ++kk) {
        const float wqv = lw[0][kk * DIM + oc];
        const float wkv = lw[1][kk * DIM + oc];
        const float wvv = lw[2][kk * DIM + oc];
        const float wsv = lw[3][kk * DIM + oc];
        #pragma unroll
        for (int r = 0; r < 4; ++r) {
            const float xv = lx[nl * 4 + r][kk];
            aq[r]  = fmaf(xv, wqv, aq[r]);
            ak[r]  = fmaf(xv, wkv, ak[r]);
            av[r]  = fmaf(xv, wvv, av[r]);
            as_[r] = fmaf(xv, wsv, as_[r]);
        }
    }
    const float bqv = bq[oc], bkv = bk[oc], bvv = bv[oc], bsv = bsk[oc];
    #pragma unroll
    for (int r = 0; r < 4; ++r) {
        const float qv = aq[r] + bqv;
        lq[nl * 4 + r][oc] = qv;
        const int n = base + nl * 4 + r;
        if (n < n_nodes) {
            q[(size_t)n * DIM + oc]       = qv;
            kv[(size_t)n * 128 + oc]      = ak[r] + bkv;
            kv[(size_t)n * 128 + 64 + oc] = av[r] + bvv;
            agg[(size_t)n * DIM + oc]     = as_[r] + bsv;   // root skip
        }
    }
    __syncthreads();

    // qwe[n][j] = sum_c q[n][c] * We[j][c]
    {
        const int j2 = tid & 31;
        const int rr = tid >> 5;   // 0..7
        #pragma unroll
        for (int t = 0; t < 2; ++t) {
            const int r = rr * 2 + t;
            float acc = 0.f;
            #pragma unroll 8
            for (int c = 0; c < DIM; ++c)
                acc = fmaf(lq[r][c], lwe_t[c * 33 + j2], acc);
            const int n = base + r;
            if (n < n_nodes) qwe[(size_t)n * DEA + j2] = acc;
        }
    }
}

// ---------------------------------------------------------------------------
// CSR build over dst: histogram -> exclusive scan -> scatter (pair = eid,src)
// ---------------------------------------------------------------------------
__global__ __launch_bounds__(256) void hist_kernel(
    const int* __restrict__ dst, int* __restrict__ counts, int n_edges, int n_nodes)
{
    const int eid = blockIdx.x * 256 + threadIdx.x;
    if (eid >= n_edges) return;
    int d = dst[eid];
    d = (d < 0) ? 0 : ((d >= n_nodes) ? n_nodes - 1 : d);
    atomicAdd(&counts[d], 1);
}

__global__ __launch_bounds__(1024) void scan_kernel(
    int* __restrict__ counts_cursor, int* __restrict__ row_ptr, int n)
{
    __shared__ int ls[1024];
    __shared__ int carry;
    const int tid = threadIdx.x;
    if (tid == 0) carry = 0;
    __syncthreads();
    for (int base = 0; base < n; base += 1024) {
        const int idx = base + tid;
        const int val = (idx < n) ? counts_cursor[idx] : 0;
        ls[tid] = val;
        __syncthreads();
        for (int off = 1; off < 1024; off <<= 1) {
            int t = (tid >= off) ? ls[tid - off] : 0;
            __syncthreads();
            if (tid >= off) ls[tid] += t;
            __syncthreads();
        }
        const int excl = ls[tid] - val + carry;
        if (idx < n) { row_ptr[idx] = excl; counts_cursor[idx] = excl; }
        __syncthreads();
        if (tid == 0) carry += ls[1023];
        __syncthreads();
    }
    if (tid == 0) row_ptr[n] = carry;
}

__global__ __launch_bounds__(256) void scatter_kernel(
    const int* __restrict__ dst, const int* __restrict__ src,
    int* __restrict__ cursor, int2* __restrict__ pair, int n_edges, int n_nodes)
{
    const int eid = blockIdx.x * 256 + threadIdx.x;
    if (eid >= n_edges) return;
    int d = dst[eid];
    d = (d < 0) ? 0 : ((d >= n_nodes) ? n_nodes - 1 : d);
    int s = src[eid];
    s = (s < 0) ? 0 : ((s >= n_nodes) ? n_nodes - 1 : s);
    const int pos = atomicAdd(&cursor[d], 1);
    pair[pos] = make_int2(eid, s);
}

// ---------------------------------------------------------------------------
// Fused aggregation v3: one wave per dst node; 4 edge-groups x 16 lanes;
// lane holds 4 channels + 2 edge-attr slots. e=ea@We pulled out of the loop:
//   score = (q.k[src] + qwe.ea)/8 ;  msg = sum p*v[src] ; sea = sum p*ea
//   out   = relu(skip + (msg + sea@We)/l)
// ---------------------------------------------------------------------------
__global__ __launch_bounds__(256) void fused_edge_kernel(
    const float* __restrict__ q, const float* __restrict__ qwe,
    const float* __restrict__ kv, const float* __restrict__ ea,
    const float* __restrict__ we, const float* __restrict__ aggskip,
    const int* __restrict__ row_ptr, const int2* __restrict__ pair,
    float* __restrict__ h_out, int n_nodes)
{
    __shared__ float lw[DEA * DIM];   // 8 KB, row-major [32][64]
    const int tid = threadIdx.x;
    {
        const float4* s4 = (const float4*)we;
        float4* d4 = (float4*)lw;
        d4[tid] = s4[tid];
        d4[tid + 256] = s4[tid + 256];
    }
    __syncthreads();

    const int wave = tid >> 6;
    const int lane = tid & 63;
    const int g = lane >> 4;
    const int j = lane & 15;
    const int node = blockIdx.x * 4 + wave;
    if (node >= n_nodes) return;

    const float4 q4   = *(const float4*)&q[(size_t)node * DIM + j * 4];
    const float2 qwe2 = *(const float2*)&qwe[(size_t)node * DEA + j * 2];
    const int beg = row_ptr[node], end = row_ptr[node + 1];

    float m = -3.0e38f, l = 0.f;
    float4 msg = make_float4(0.f, 0.f, 0.f, 0.f);
    float2 sea = make_float2(0.f, 0.f);

    if (beg < end) {
        int2 pr = pair[(beg + g < end) ? (beg + g) : (end - 1)];
        for (int i0 = beg; i0 < end; i0 += 4) {
            const bool act = (i0 + g) < end;
            const int eid = pr.x;
            const int s   = pr.y;
            const float4* kvp = (const float4*)&kv[(size_t)s * 128];
            const float4 k4 = kvp[j];
            const float4 v4 = kvp[16 + j];
            const float2 ea2 = *(const float2*)&ea[(size_t)eid * DEA + j * 2];
            const int inext = i0 + 4 + g;
            if (inext < end) pr = pair[inext];   // prefetch next group pair

            float t = fmaf(q4.x, k4.x, qwe2.x * ea2.x);
            t = fmaf(q4.y, k4.y, t);
            t = fmaf(q4.z, k4.z, t);
            t = fmaf(q4.w, k4.w, t);
            t = fmaf(qwe2.y, ea2.y, t);
            t += __shfl_xor(t, 1, 64);
            t += __shfl_xor(t, 2, 64);
            t += __shfl_xor(t, 4, 64);
            t += __shfl_xor(t, 8, 64);
            const float score = act ? t * 0.125f : -3.0e38f;

            const float mn = fmaxf(m, score);
            const float p  = act ? __expf(score - mn) : 0.f;
            const float sc = __expf(m - mn);
            l = l * sc + p;
            msg.x = fmaf(p, v4.x, msg.x * sc);
            msg.y = fmaf(p, v4.y, msg.y * sc);
            msg.z = fmaf(p, v4.z, msg.z * sc);
            msg.w = fmaf(p, v4.w, msg.w * sc);
            sea.x = fmaf(p, ea2.x, sea.x * sc);
            sea.y = fmaf(p, ea2.y, sea.y * sc);
            m = mn;
        }
    }

    // merge the 4 groups (xor 16, then 32)
    #pragma unroll
    for (int off = 16; off <= 32; off <<= 1) {
        const float m2 = __shfl_xor(m, off, 64);
        const float l2 = __shfl_xor(l, off, 64);
        float4 msg2;
        msg2.x = __shfl_xor(msg.x, off, 64);
        msg2.y = __shfl_xor(msg.y, off, 64);
        msg2.z = __shfl_xor(msg.z, off, 64);
        msg2.w = __shfl_xor(msg.w, off, 64);
        float2 sea2;
        sea2.x = __shfl_xor(sea.x, off, 64);
        sea2.y = __shfl_xor(sea.y, off, 64);
        const float mn = fmaxf(m, m2);
        const float s1 = __expf(m - mn);
        const float s2 = __expf(m2 - mn);
        l = l * s1 + l2 * s2;
        msg.x = msg.x * s1 + msg2.x * s2;
        msg.y = msg.y * s1 + msg2.y * s2;
        msg.z = msg.z * s1 + msg2.z * s2;
        msg.w = msg.w * s1 + msg2.w * s2;
        sea.x = sea.x * s1 + sea2.x * s2;
        sea.y = sea.y * s1 + sea2.y * s2;
        m = mn;
    }

    // epilogue: e = sea @ We for this lane's 4 channels (sea lives on j=0..15)
    const float4* lw4 = (const float4*)lw;
    float4 e4 = make_float4(0.f, 0.f, 0.f, 0.f);
    #pragma unroll
    for (int tt = 0; tt < 16; ++tt) {
        const float sx = __shfl(sea.x, tt, 64);
        const float sy = __shfl(sea.y, tt, 64);
        const float4 w0 = lw4[(2 * tt) * 16 + j];
        const float4 w1 = lw4[(2 * tt + 1) * 16 + j];
        e4.x = fmaf(sx, w0.x, fmaf(sy, w1.x, e4.x));
        e4.y = fmaf(sx, w0.y, fmaf(sy, w1.y, e4.y));
        e4.z = fmaf(sx, w0.z, fmaf(sy, w1.z, e4.z));
        e4.w = fmaf(sx, w0.w, fmaf(sy, w1.w, e4.w));
    }

    if (lane < 16) {
        const float inv = (l > 0.f) ? (1.f / l) : 0.f;
        const float4 sk = *(const float4*)&aggskip[(size_t)node * DIM + j * 4];
        float4 o;
        o.x = fmaxf(fmaf(msg.x + e4.x, inv, sk.x), 0.f);
        o.y = fmaxf(fmaf(msg.y + e4.y, inv, sk.y), 0.f);
        o.z = fmaxf(fmaf(msg.z + e4.z, inv, sk.z), 0.f);
        o.w = fmaxf(fmaf(msg.w + e4.w, inv, sk.w), 0.f);
        *(float4*)&h_out[(size_t)node * DIM + j * 4] = o;
    }
}

// ---------------------------------------------------------------------------
// Final: out = relu(concat(h1,h2) @ skip_w + skip_b), K=128
// ---------------------------------------------------------------------------
__global__ __launch_bounds__(256) void final_kernel(
    const float* __restrict__ h1, const float* __restrict__ h2,
    const float* __restrict__ w, const float* __restrict__ b,
    float* __restrict__ out, int n_nodes)
{
    __shared__ float lw[128 * DIM];   // 32 KB
    __shared__ float lx[16][128];     // 8 KB
    const int tid = threadIdx.x;
    {
        const float4* s4 = (const float4*)w;
        float4* d4 = (float4*)lw;
        #pragma unroll
        for (int i = 0; i < 8; ++i) d4[tid + i * 256] = s4[tid + i * 256];
    }
    const int base = blockIdx.x * 16;
    {
        #pragma unroll
        for (int t = 0; t < 2; ++t) {
            const int f = tid + t * 256;
            const int r = f >> 5;
            const int cf = f & 31;
            const int n = base + r;
            float4 val = make_float4(0.f, 0.f, 0.f, 0.f);
            if (n < n_nodes) {
                if (cf < 16) val = *(const float4*)&h1[(size_t)n * DIM + cf * 4];
                else         val = *(const float4*)&h2[(size_t)n * DIM + (cf - 16) * 4];
            }
            *(float4*)&lx[r][cf * 4] = val;
        }
    }
    __syncthreads();

    const int oc = tid & 63;
    const int nl = tid >> 6;
    float acc[4] = {0, 0, 0, 0};
    #pragma unroll 8
    for (int kk = 0; kk < 128; ++kk) {
        const float wv = lw[kk * DIM + oc];
        #pragma unroll
        for (int r = 0; r < 4; ++r)
            acc[r] = fmaf(lx[nl * 4 + r][kk], wv, acc[r]);
    }
    const float bv = b[oc];
    #pragma unroll
    for (int r = 0; r < 4; ++r) {
        const int n = base + nl * 4 + r;
        if (n < n_nodes) out[(size_t)n * DIM + oc] = fmaxf(acc[r] + bv, 0.f);
    }
}

// ---------------------------------------------------------------------------
extern "C" void kernel_launch(void* const* d_in, const int* in_sizes, int n_in,
                              void* d_out, int out_size, void* d_ws, size_t ws_size,
                              hipStream_t stream)
{
    const float* x     = (const float*)d_in[0];
    const int*   ei    = (const int*)d_in[1];
    const float* eattr = (const float*)d_in[2];
    const float *q1w = (const float*)d_in[3],  *q1b = (const float*)d_in[4];
    const float *k1w = (const float*)d_in[5],  *k1b = (const float*)d_in[6];
    const float *v1w = (const float*)d_in[7],  *v1b = (const float*)d_in[8];
    const float *e1w = (const float*)d_in[9];
    const float *s1w = (const float*)d_in[10], *s1b = (const float*)d_in[11];
    const float *q2w = (const float*)d_in[12], *q2b = (const float*)d_in[13];
    const float *k2w = (const float*)d_in[14], *k2b = (const float*)d_in[15];
    const float *v2w = (const float*)d_in[16], *v2b = (const float*)d_in[17];
    const float *e2w = (const float*)d_in[18];
    const float *s2w = (const float*)d_in[19], *s2b = (const float*)d_in[20];
    const float *skw = (const float*)d_in[21], *skb = (const float*)d_in[22];

    const int N = in_sizes[0] / DIM;
    const int E = in_sizes[1] / 2;
    const int* src = ei;
    const int* dst = ei + E;

    float* ws = (float*)d_ws;
    const size_t nf = (size_t)N * DIM;
    float* q    = ws;             // nf
    float* kv   = q + nf;         // 2*nf
    float* agg  = kv + 2 * nf;    // nf
    float* h1   = agg + nf;       // nf
    float* h2   = h1 + nf;        // nf
    float* qwe  = h2 + nf;        // 32*N
    int2* pair    = (int2*)(qwe + (size_t)DEA * N);  // E int2 (8B-aligned)
    int* row_ptr  = (int*)(pair + E);                // N+1
    int* cursor   = row_ptr + N + 1;                 // N

    const int nblk = (N + 15) / 16;
    const int eblk = (E + 255) / 256;
    const int fblk = (N + 3) / 4;

    // ---------------- CSR over dst (shared by both layers) ----------------
    hipMemsetAsync(cursor, 0, (size_t)N * sizeof(int), stream);
    hist_kernel<<<eblk, 256, 0, stream>>>(dst, cursor, E, N);
    scan_kernel<<<1, 1024, 0, stream>>>(cursor, row_ptr, N);
    scatter_kernel<<<eblk, 256, 0, stream>>>(dst, src, cursor, pair, E, N);

    // ---------------- layer 1 ----------------
    node_lin_kernel<<<nblk, 256, 0, stream>>>(x, q1w, q1b, k1w, k1b, v1w, v1b,
                                              s1w, s1b, e1w, q, kv, agg, qwe, N);
    fused_edge_kernel<<<fblk, 256, 0, stream>>>(q, qwe, kv, eattr, e1w, agg,
                                                row_ptr, pair, h1, N);

    // ---------------- layer 2 ----------------
    node_lin_kernel<<<nblk, 256, 0, stream>>>(h1, q2w, q2b, k2w, k2b, v2w, v2b,
                                              s2w, s2b, e2w, q, kv, agg, qwe, N);
    fused_edge_kernel<<<fblk, 256, 0, stream>>>(q, qwe, kv, eattr, e2w, agg,
                                                row_ptr, pair, h2, N);

    // ---------------- final skip MLP ----------------
    final_kernel<<<nblk, 256, 0, stream>>>(h1, h2, skw, skb, (float*)d_out, N);
}

// Round 5
// 478.143 us; speedup vs baseline: 1.8675x; 1.1342x over previous
//
#include <hip/hip_runtime.h>

#define DIM 64
#define DEA 32

// ---------------------------------------------------------------------------
// One-time: combined score weight  M = Wq @ We^T  [64][32],  bqe = bq @ We^T.
// grid = 2 (layer 1, layer 2).
// ---------------------------------------------------------------------------
__global__ __launch_bounds__(256) void wqe_prep_kernel(
    const float* __restrict__ wq1, const float* __restrict__ bq1, const float* __restrict__ we1,
    const float* __restrict__ wq2, const float* __restrict__ bq2, const float* __restrict__ we2,
    float* __restrict__ w1out, float* __restrict__ b1out,
    float* __restrict__ w2out, float* __restrict__ b2out)
{
    const float* wq = blockIdx.x ? wq2 : wq1;
    const float* bq = blockIdx.x ? bq2 : bq1;
    const float* we = blockIdx.x ? we2 : we1;
    float* wout = blockIdx.x ? w2out : w1out;
    float* bout = blockIdx.x ? b2out : b1out;

    __shared__ float lq[64 * 64];     // Wq[c][o], 16 KB
    __shared__ float lweT[64 * 33];   // We^T [o][j], padded
    const int tid = threadIdx.x;
    {
        const float4* s4 = (const float4*)wq;
        float4* d4 = (float4*)lq;
        #pragma unroll
        for (int i = 0; i < 4; ++i) d4[tid + i * 256] = s4[tid + i * 256];
        const float4* e4 = (const float4*)we;   // we[32][64]
        #pragma unroll
        for (int t = 0; t < 2; ++t) {
            const int f = tid + t * 256;
            const int j = f >> 4;
            const int o4 = (f & 15) * 4;
            const float4 v = e4[f];
            lweT[(o4 + 0) * 33 + j] = v.x;
            lweT[(o4 + 1) * 33 + j] = v.y;
            lweT[(o4 + 2) * 33 + j] = v.z;
            lweT[(o4 + 3) * 33 + j] = v.w;
        }
    }
    __syncthreads();
    const int j = tid & 31;
    const int c0 = (tid >> 5) * 8;
    for (int c = c0; c < c0 + 8; ++c) {
        float acc = 0.f;
        #pragma unroll 8
        for (int o = 0; o < 64; ++o) acc = fmaf(lq[c * 64 + o], lweT[o * 33 + j], acc);
        wout[c * 32 + j] = acc;
    }
    if (tid < 32) {
        float acc = 0.f;
        #pragma unroll 8
        for (int o = 0; o < 64; ++o) acc = fmaf(bq[o], lweT[o * 33 + tid], acc);
        bout[tid] = acc;
    }
}

// ---------------------------------------------------------------------------
// Node linear v2: 32 nodes/block, wave m owns matrix m (q,k,v,skip).
// Weights staged in 16-row chunks (16 KB); x^T resident (9 KB); Wqe (8 KB).
// qwe = x @ Wqe + bqe computed off the same x^T tile.
// ---------------------------------------------------------------------------
__global__ __launch_bounds__(256) void node_lin_kernel(
    const float* __restrict__ x,
    const float* __restrict__ wq, const float* __restrict__ bq,
    const float* __restrict__ wk, const float* __restrict__ bk,
    const float* __restrict__ wv, const float* __restrict__ bv,
    const float* __restrict__ wsk, const float* __restrict__ bsk,
    const float* __restrict__ wqe_w, const float* __restrict__ bqe,
    float* __restrict__ q, float* __restrict__ kv,
    float* __restrict__ agg, float* __restrict__ qwe, int n_nodes)
{
    __shared__ float lw[16 * 256];    // 16 KB  [kk][m*64+oc]
    __shared__ float lxT[64 * 36];    // 9 KB   x^T [c][node], pad 36
    __shared__ float lwqe[64 * 32];   // 8 KB   [c][j]
    const int tid = threadIdx.x;
    const int base = blockIdx.x * 32;

    // stage x^T and Wqe
    {
        #pragma unroll
        for (int t = 0; t < 2; ++t) {
            const int f = tid + t * 256;          // 0..511
            const int node = f >> 4;              // 0..31
            const int c4 = (f & 15) * 4;
            const int n = base + node;
            float4 val = make_float4(0.f, 0.f, 0.f, 0.f);
            if (n < n_nodes) val = *(const float4*)&x[(size_t)n * DIM + c4];
            lxT[(c4 + 0) * 36 + node] = val.x;
            lxT[(c4 + 1) * 36 + node] = val.y;
            lxT[(c4 + 2) * 36 + node] = val.z;
            lxT[(c4 + 3) * 36 + node] = val.w;
        }
        const float4* s4 = (const float4*)wqe_w;
        float4* d4 = (float4*)lwqe;
        d4[tid] = s4[tid];
        d4[tid + 256] = s4[tid + 256];
    }

    const int m = tid >> 6;    // wave index = output matrix
    const int oc = tid & 63;
    const float* wsrc = (m == 0) ? wq : (m == 1) ? wk : (m == 2) ? wv : wsk;
    const float bias = ((m == 0) ? bq : (m == 1) ? bk : (m == 2) ? bv : bsk)[oc];

    float acc[32];
    #pragma unroll
    for (int r = 0; r < 32; ++r) acc[r] = 0.f;

    for (int kc = 0; kc < 4; ++kc) {
        __syncthreads();
        // each wave stages its own matrix's 16x64 chunk (4 float4/lane)
        #pragma unroll
        for (int i = 0; i < 4; ++i) {
            const int f = oc + i * 64;            // 0..255
            const int kk = f >> 4;
            const int c4 = (f & 15) * 4;
            const float4 w4 = *(const float4*)&wsrc[(size_t)(kc * 16 + kk) * DIM + c4];
            *(float4*)&lw[kk * 256 + m * 64 + c4] = w4;
        }
        __syncthreads();
        #pragma unroll
        for (int kk = 0; kk < 16; ++kk) {
            const float wv_ = lw[kk * 256 + tid];
            const float* xrow = &lxT[(kc * 16 + kk) * 36];
            #pragma unroll
            for (int r4 = 0; r4 < 8; ++r4) {
                const float4 xv = *(const float4*)&xrow[r4 * 4];
                acc[r4 * 4 + 0] = fmaf(xv.x, wv_, acc[r4 * 4 + 0]);
                acc[r4 * 4 + 1] = fmaf(xv.y, wv_, acc[r4 * 4 + 1]);
                acc[r4 * 4 + 2] = fmaf(xv.z, wv_, acc[r4 * 4 + 2]);
                acc[r4 * 4 + 3] = fmaf(xv.w, wv_, acc[r4 * 4 + 3]);
            }
        }
    }

    #pragma unroll
    for (int r = 0; r < 32; ++r) {
        const int n = base + r;
        if (n < n_nodes) {
            const float val = acc[r] + bias;
            if (m == 0)      q[(size_t)n * DIM + oc]        = val;
            else if (m == 1) kv[(size_t)n * 128 + oc]       = val;
            else if (m == 2) kv[(size_t)n * 128 + 64 + oc]  = val;
            else             agg[(size_t)n * DIM + oc]      = val;   // root skip
        }
    }

    // qwe phase: 32 nodes x 32 cols, 4 outputs/thread, reads resident lxT/lwqe
    {
        const int j = tid & 31;
        const int r0 = (tid >> 5) * 4;
        float a0 = 0.f, a1 = 0.f, a2 = 0.f, a3 = 0.f;
        #pragma unroll 8
        for (int c = 0; c < DIM; ++c) {
            const float wv_ = lwqe[c * 32 + j];
            const float4 xv = *(const float4*)&lxT[c * 36 + r0];
            a0 = fmaf(xv.x, wv_, a0);
            a1 = fmaf(xv.y, wv_, a1);
            a2 = fmaf(xv.z, wv_, a2);
            a3 = fmaf(xv.w, wv_, a3);
        }
        const float bb = bqe[j];
        const float av[4] = {a0 + bb, a1 + bb, a2 + bb, a3 + bb};
        #pragma unroll
        for (int i = 0; i < 4; ++i) {
            const int n = base + r0 + i;
            if (n < n_nodes) qwe[(size_t)n * DEA + j] = av[i];
        }
    }
}

// ---------------------------------------------------------------------------
// CSR build over dst: histogram -> exclusive scan -> scatter (pair = eid,src)
// ---------------------------------------------------------------------------
__global__ __launch_bounds__(256) void hist_kernel(
    const int* __restrict__ dst, int* __restrict__ counts, int n_edges, int n_nodes)
{
    const int eid = blockIdx.x * 256 + threadIdx.x;
    if (eid >= n_edges) return;
    int d = dst[eid];
    d = (d < 0) ? 0 : ((d >= n_nodes) ? n_nodes - 1 : d);
    atomicAdd(&counts[d], 1);
}

__global__ __launch_bounds__(1024) void scan_kernel(
    int* __restrict__ counts_cursor, int* __restrict__ row_ptr, int n)
{
    __shared__ int ls[1024];
    __shared__ int carry;
    const int tid = threadIdx.x;
    if (tid == 0) carry = 0;
    __syncthreads();
    for (int base = 0; base < n; base += 1024) {
        const int idx = base + tid;
        const int val = (idx < n) ? counts_cursor[idx] : 0;
        ls[tid] = val;
        __syncthreads();
        for (int off = 1; off < 1024; off <<= 1) {
            int t = (tid >= off) ? ls[tid - off] : 0;
            __syncthreads();
            if (tid >= off) ls[tid] += t;
            __syncthreads();
        }
        const int excl = ls[tid] - val + carry;
        if (idx < n) { row_ptr[idx] = excl; counts_cursor[idx] = excl; }
        __syncthreads();
        if (tid == 0) carry += ls[1023];
        __syncthreads();
    }
    if (tid == 0) row_ptr[n] = carry;
}

__global__ __launch_bounds__(256) void scatter_kernel(
    const int* __restrict__ dst, const int* __restrict__ src,
    int* __restrict__ cursor, int2* __restrict__ pair, int n_edges, int n_nodes)
{
    const int eid = blockIdx.x * 256 + threadIdx.x;
    if (eid >= n_edges) return;
    int d = dst[eid];
    d = (d < 0) ? 0 : ((d >= n_nodes) ? n_nodes - 1 : d);
    int s = src[eid];
    s = (s < 0) ? 0 : ((s >= n_nodes) ? n_nodes - 1 : s);
    const int pos = atomicAdd(&cursor[d], 1);
    pair[pos] = make_int2(eid, s);
}

// ---------------------------------------------------------------------------
// Fused aggregation v3: one wave per dst node; 4 edge-groups x 16 lanes;
// lane holds 4 channels + 2 edge-attr slots. e=ea@We hoisted out:
//   score = (q.k[src] + qwe.ea)/8 ;  msg = sum p*v[src] ; sea = sum p*ea
//   out   = relu(skip + (msg + sea@We)/l)
// ---------------------------------------------------------------------------
__global__ __launch_bounds__(256) void fused_edge_kernel(
    const float* __restrict__ q, const float* __restrict__ qwe,
    const float* __restrict__ kv, const float* __restrict__ ea,
    const float* __restrict__ we, const float* __restrict__ aggskip,
    const int* __restrict__ row_ptr, const int2* __restrict__ pair,
    float* __restrict__ h_out, int n_nodes)
{
    __shared__ float lw[DEA * DIM];   // 8 KB, row-major [32][64]
    const int tid = threadIdx.x;
    {
        const float4* s4 = (const float4*)we;
        float4* d4 = (float4*)lw;
        d4[tid] = s4[tid];
        d4[tid + 256] = s4[tid + 256];
    }
    __syncthreads();

    const int wave = tid >> 6;
    const int lane = tid & 63;
    const int g = lane >> 4;
    const int j = lane & 15;
    const int node = blockIdx.x * 4 + wave;
    if (node >= n_nodes) return;

    const float4 q4   = *(const float4*)&q[(size_t)node * DIM + j * 4];
    const float2 qwe2 = *(const float2*)&qwe[(size_t)node * DEA + j * 2];
    const int beg = row_ptr[node], end = row_ptr[node + 1];

    float m = -3.0e38f, l = 0.f;
    float4 msg = make_float4(0.f, 0.f, 0.f, 0.f);
    float2 sea = make_float2(0.f, 0.f);

    if (beg < end) {
        int2 pr = pair[(beg + g < end) ? (beg + g) : (end - 1)];
        for (int i0 = beg; i0 < end; i0 += 4) {
            const bool act = (i0 + g) < end;
            const int eid = pr.x;
            const int s   = pr.y;
            const float4* kvp = (const float4*)&kv[(size_t)s * 128];
            const float4 k4 = kvp[j];
            const float4 v4 = kvp[16 + j];
            const float2 ea2 = *(const float2*)&ea[(size_t)eid * DEA + j * 2];
            const int inext = i0 + 4 + g;
            if (inext < end) pr = pair[inext];   // prefetch next group pair

            float t = fmaf(q4.x, k4.x, qwe2.x * ea2.x);
            t = fmaf(q4.y, k4.y, t);
            t = fmaf(q4.z, k4.z, t);
            t = fmaf(q4.w, k4.w, t);
            t = fmaf(qwe2.y, ea2.y, t);
            t += __shfl_xor(t, 1, 64);
            t += __shfl_xor(t, 2, 64);
            t += __shfl_xor(t, 4, 64);
            t += __shfl_xor(t, 8, 64);
            const float score = act ? t * 0.125f : -3.0e38f;

            const float mn = fmaxf(m, score);
            const float p  = act ? __expf(score - mn) : 0.f;
            const float sc = __expf(m - mn);
            l = l * sc + p;
            msg.x = fmaf(p, v4.x, msg.x * sc);
            msg.y = fmaf(p, v4.y, msg.y * sc);
            msg.z = fmaf(p, v4.z, msg.z * sc);
            msg.w = fmaf(p, v4.w, msg.w * sc);
            sea.x = fmaf(p, ea2.x, sea.x * sc);
            sea.y = fmaf(p, ea2.y, sea.y * sc);
            m = mn;
        }
    }

    #pragma unroll
    for (int off = 16; off <= 32; off <<= 1) {
        const float m2 = __shfl_xor(m, off, 64);
        const float l2 = __shfl_xor(l, off, 64);
        float4 msg2;
        msg2.x = __shfl_xor(msg.x, off, 64);
        msg2.y = __shfl_xor(msg.y, off, 64);
        msg2.z = __shfl_xor(msg.z, off, 64);
        msg2.w = __shfl_xor(msg.w, off, 64);
        float2 sea2;
        sea2.x = __shfl_xor(sea.x, off, 64);
        sea2.y = __shfl_xor(sea.y, off, 64);
        const float mn = fmaxf(m, m2);
        const float s1 = __expf(m - mn);
        const float s2 = __expf(m2 - mn);
        l = l * s1 + l2 * s2;
        msg.x = msg.x * s1 + msg2.x * s2;
        msg.y = msg.y * s1 + msg2.y * s2;
        msg.z = msg.z * s1 + msg2.z * s2;
        msg.w = msg.w * s1 + msg2.w * s2;
        sea.x = sea.x * s1 + sea2.x * s2;
        sea.y = sea.y * s1 + sea2.y * s2;
        m = mn;
    }

    const float4* lw4 = (const float4*)lw;
    float4 e4 = make_float4(0.f, 0.f, 0.f, 0.f);
    #pragma unroll
    for (int tt = 0; tt < 16; ++tt) {
        const float sx = __shfl(sea.x, tt, 64);
        const float sy = __shfl(sea.y, tt, 64);
        const float4 w0 = lw4[(2 * tt) * 16 + j];
        const float4 w1 = lw4[(2 * tt + 1) * 16 + j];
        e4.x = fmaf(sx, w0.x, fmaf(sy, w1.x, e4.x));
        e4.y = fmaf(sx, w0.y, fmaf(sy, w1.y, e4.y));
        e4.z = fmaf(sx, w0.z, fmaf(sy, w1.z, e4.z));
        e4.w = fmaf(sx, w0.w, fmaf(sy, w1.w, e4.w));
    }

    if (lane < 16) {
        const float inv = (l > 0.f) ? (1.f / l) : 0.f;
        const float4 sk = *(const float4*)&aggskip[(size_t)node * DIM + j * 4];
        float4 o;
        o.x = fmaxf(fmaf(msg.x + e4.x, inv, sk.x), 0.f);
        o.y = fmaxf(fmaf(msg.y + e4.y, inv, sk.y), 0.f);
        o.z = fmaxf(fmaf(msg.z + e4.z, inv, sk.z), 0.f);
        o.w = fmaxf(fmaf(msg.w + e4.w, inv, sk.w), 0.f);
        *(float4*)&h_out[(size_t)node * DIM + j * 4] = o;
    }
}

// ---------------------------------------------------------------------------
// Final: out = relu(concat(h1,h2) @ skip_w + skip_b), K=128
// ---------------------------------------------------------------------------
__global__ __launch_bounds__(256) void final_kernel(
    const float* __restrict__ h1, const float* __restrict__ h2,
    const float* __restrict__ w, const float* __restrict__ b,
    float* __restrict__ out, int n_nodes)
{
    __shared__ float lw[128 * DIM];   // 32 KB
    __shared__ float lx[16][128];     // 8 KB
    const int tid = threadIdx.x;
    {
        const float4* s4 = (const float4*)w;
        float4* d4 = (float4*)lw;
        #pragma unroll
        for (int i = 0; i < 8; ++i) d4[tid + i * 256] = s4[tid + i * 256];
    }
    const int base = blockIdx.x * 16;
    {
        #pragma unroll
        for (int t = 0; t < 2; ++t) {
            const int f = tid + t * 256;
            const int r = f >> 5;
            const int cf = f & 31;
            const int n = base + r;
            float4 val = make_float4(0.f, 0.f, 0.f, 0.f);
            if (n < n_nodes) {
                if (cf < 16) val = *(const float4*)&h1[(size_t)n * DIM + cf * 4];
                else         val = *(const float4*)&h2[(size_t)n * DIM + (cf - 16) * 4];
            }
            *(float4*)&lx[r][cf * 4] = val;
        }
    }
    __syncthreads();

    const int oc = tid & 63;
    const int nl = tid >> 6;
    float acc[4] = {0, 0, 0, 0};
    #pragma unroll 8
    for (int kk = 0; kk < 128; ++kk) {
        const float wv = lw[kk * DIM + oc];
        #pragma unroll
        for (int r = 0; r < 4; ++r)
            acc[r] = fmaf(lx[nl * 4 + r][kk], wv, acc[r]);
    }
    const float bv = b[oc];
    #pragma unroll
    for (int r = 0; r < 4; ++r) {
        const int n = base + nl * 4 + r;
        if (n < n_nodes) out[(size_t)n * DIM + oc] = fmaxf(acc[r] + bv, 0.f);
    }
}

// ---------------------------------------------------------------------------
extern "C" void kernel_launch(void* const* d_in, const int* in_sizes, int n_in,
                              void* d_out, int out_size, void* d_ws, size_t ws_size,
                              hipStream_t stream)
{
    const float* x     = (const float*)d_in[0];
    const int*   ei    = (const int*)d_in[1];
    const float* eattr = (const float*)d_in[2];
    const float *q1w = (const float*)d_in[3],  *q1b = (const float*)d_in[4];
    const float *k1w = (const float*)d_in[5],  *k1b = (const float*)d_in[6];
    const float *v1w = (const float*)d_in[7],  *v1b = (const float*)d_in[8];
    const float *e1w = (const float*)d_in[9];
    const float *s1w = (const float*)d_in[10], *s1b = (const float*)d_in[11];
    const float *q2w = (const float*)d_in[12], *q2b = (const float*)d_in[13];
    const float *k2w = (const float*)d_in[14], *k2b = (const float*)d_in[15];
    const float *v2w = (const float*)d_in[16], *v2b = (const float*)d_in[17];
    const float *e2w = (const float*)d_in[18];
    const float *s2w = (const float*)d_in[19], *s2b = (const float*)d_in[20];
    const float *skw = (const float*)d_in[21], *skb = (const float*)d_in[22];

    const int N = in_sizes[0] / DIM;
    const int E = in_sizes[1] / 2;
    const int* src = ei;
    const int* dst = ei + E;

    float* ws = (float*)d_ws;
    const size_t nf = (size_t)N * DIM;
    float* q    = ws;             // nf
    float* kv   = q + nf;         // 2*nf
    float* agg  = kv + 2 * nf;    // nf
    float* h1   = agg + nf;       // nf
    float* h2   = h1 + nf;        // nf
    float* qwe  = h2 + nf;        // 32*N
    int2* pair    = (int2*)(qwe + (size_t)DEA * N);  // E int2
    int* row_ptr  = (int*)(pair + E);                // N+1
    int* cursor   = row_ptr + N + 1;                 // N
    float* wqeW1  = (float*)(cursor + N);            // 2048
    float* bqe1   = wqeW1 + 64 * 32;                 // 32
    float* wqeW2  = bqe1 + 32;                       // 2048
    float* bqe2   = wqeW2 + 64 * 32;                 // 32

    const int nblk = (N + 31) / 32;
    const int eblk = (E + 255) / 256;
    const int fblk = (N + 3) / 4;
    const int finblk = (N + 15) / 16;

    // ---------------- CSR over dst + combined score weights ----------------
    hipMemsetAsync(cursor, 0, (size_t)N * sizeof(int), stream);
    hist_kernel<<<eblk, 256, 0, stream>>>(dst, cursor, E, N);
    scan_kernel<<<1, 1024, 0, stream>>>(cursor, row_ptr, N);
    scatter_kernel<<<eblk, 256, 0, stream>>>(dst, src, cursor, pair, E, N);
    wqe_prep_kernel<<<2, 256, 0, stream>>>(q1w, q1b, e1w, q2w, q2b, e2w,
                                           wqeW1, bqe1, wqeW2, bqe2);

    // ---------------- layer 1 ----------------
    node_lin_kernel<<<nblk, 256, 0, stream>>>(x, q1w, q1b, k1w, k1b, v1w, v1b,
                                              s1w, s1b, wqeW1, bqe1,
                                              q, kv, agg, qwe, N);
    fused_edge_kernel<<<fblk, 256, 0, stream>>>(q, qwe, kv, eattr, e1w, agg,
                                                row_ptr, pair, h1, N);

    // ---------------- layer 2 ----------------
    node_lin_kernel<<<nblk, 256, 0, stream>>>(h1, q2w, q2b, k2w, k2b, v2w, v2b,
                                              s2w, s2b, wqeW2, bqe2,
                                              q, kv, agg, qwe, N);
    fused_edge_kernel<<<fblk, 256, 0, stream>>>(q, qwe, kv, eattr, e2w, agg,
                                                row_ptr, pair, h2, N);

    // ---------------- final skip MLP ----------------
    final_kernel<<<finblk, 256, 0, stream>>>(h1, h2, skw, skb, (float*)d_out, N);
}

// Round 6
// 395.408 us; speedup vs baseline: 2.2582x; 1.2092x over previous
//
#include <hip/hip_runtime.h>

#define DIM 64
#define DEA 32

// ---------------------------------------------------------------------------
// One-time: combined score weight  M = Wq @ We^T  [64][32],  bqe = bq @ We^T.
// grid = 2 (layer 1, layer 2).
// ---------------------------------------------------------------------------
__global__ __launch_bounds__(256) void wqe_prep_kernel(
    const float* __restrict__ wq1, const float* __restrict__ bq1, const float* __restrict__ we1,
    const float* __restrict__ wq2, const float* __restrict__ bq2, const float* __restrict__ we2,
    float* __restrict__ w1out, float* __restrict__ b1out,
    float* __restrict__ w2out, float* __restrict__ b2out)
{
    const float* wq = blockIdx.x ? wq2 : wq1;
    const float* bq = blockIdx.x ? bq2 : bq1;
    const float* we = blockIdx.x ? we2 : we1;
    float* wout = blockIdx.x ? w2out : w1out;
    float* bout = blockIdx.x ? b2out : b1out;

    __shared__ float lq[64 * 64];     // Wq[c][o], 16 KB
    __shared__ float lweT[64 * 33];   // We^T [o][j], padded
    const int tid = threadIdx.x;
    {
        const float4* s4 = (const float4*)wq;
        float4* d4 = (float4*)lq;
        #pragma unroll
        for (int i = 0; i < 4; ++i) d4[tid + i * 256] = s4[tid + i * 256];
        const float4* e4 = (const float4*)we;   // we[32][64]
        #pragma unroll
        for (int t = 0; t < 2; ++t) {
            const int f = tid + t * 256;
            const int j = f >> 4;
            const int o4 = (f & 15) * 4;
            const float4 v = e4[f];
            lweT[(o4 + 0) * 33 + j] = v.x;
            lweT[(o4 + 1) * 33 + j] = v.y;
            lweT[(o4 + 2) * 33 + j] = v.z;
            lweT[(o4 + 3) * 33 + j] = v.w;
        }
    }
    __syncthreads();
    const int j = tid & 31;
    const int c0 = (tid >> 5) * 8;
    for (int c = c0; c < c0 + 8; ++c) {
        float acc = 0.f;
        #pragma unroll 8
        for (int o = 0; o < 64; ++o) acc = fmaf(lq[c * 64 + o], lweT[o * 33 + j], acc);
        wout[c * 32 + j] = acc;
    }
    if (tid < 32) {
        float acc = 0.f;
        #pragma unroll 8
        for (int o = 0; o < 64; ++o) acc = fmaf(bq[o], lweT[o * 33 + tid], acc);
        bout[tid] = acc;
    }
}

// ---------------------------------------------------------------------------
// Node linear v2: 32 nodes/block, wave m owns matrix m (q,k,v,skip).
// ---------------------------------------------------------------------------
__global__ __launch_bounds__(256) void node_lin_kernel(
    const float* __restrict__ x,
    const float* __restrict__ wq, const float* __restrict__ bq,
    const float* __restrict__ wk, const float* __restrict__ bk,
    const float* __restrict__ wv, const float* __restrict__ bv,
    const float* __restrict__ wsk, const float* __restrict__ bsk,
    const float* __restrict__ wqe_w, const float* __restrict__ bqe,
    float* __restrict__ q, float* __restrict__ kv,
    float* __restrict__ agg, float* __restrict__ qwe, int n_nodes)
{
    __shared__ float lw[16 * 256];    // 16 KB  [kk][m*64+oc]
    __shared__ float lxT[64 * 36];    // 9 KB   x^T [c][node], pad 36
    __shared__ float lwqe[64 * 32];   // 8 KB   [c][j]
    const int tid = threadIdx.x;
    const int base = blockIdx.x * 32;

    {
        #pragma unroll
        for (int t = 0; t < 2; ++t) {
            const int f = tid + t * 256;          // 0..511
            const int node = f >> 4;              // 0..31
            const int c4 = (f & 15) * 4;
            const int n = base + node;
            float4 val = make_float4(0.f, 0.f, 0.f, 0.f);
            if (n < n_nodes) val = *(const float4*)&x[(size_t)n * DIM + c4];
            lxT[(c4 + 0) * 36 + node] = val.x;
            lxT[(c4 + 1) * 36 + node] = val.y;
            lxT[(c4 + 2) * 36 + node] = val.z;
            lxT[(c4 + 3) * 36 + node] = val.w;
        }
        const float4* s4 = (const float4*)wqe_w;
        float4* d4 = (float4*)lwqe;
        d4[tid] = s4[tid];
        d4[tid + 256] = s4[tid + 256];
    }

    const int m = tid >> 6;    // wave index = output matrix
    const int oc = tid & 63;
    const float* wsrc = (m == 0) ? wq : (m == 1) ? wk : (m == 2) ? wv : wsk;
    const float bias = ((m == 0) ? bq : (m == 1) ? bk : (m == 2) ? bv : bsk)[oc];

    float acc[32];
    #pragma unroll
    for (int r = 0; r < 32; ++r) acc[r] = 0.f;

    for (int kc = 0; kc < 4; ++kc) {
        __syncthreads();
        #pragma unroll
        for (int i = 0; i < 4; ++i) {
            const int f = oc + i * 64;            // 0..255
            const int kk = f >> 4;
            const int c4 = (f & 15) * 4;
            const float4 w4 = *(const float4*)&wsrc[(size_t)(kc * 16 + kk) * DIM + c4];
            *(float4*)&lw[kk * 256 + m * 64 + c4] = w4;
        }
        __syncthreads();
        #pragma unroll
        for (int kk = 0; kk < 16; ++kk) {
            const float wv_ = lw[kk * 256 + tid];
            const float* xrow = &lxT[(kc * 16 + kk) * 36];
            #pragma unroll
            for (int r4 = 0; r4 < 8; ++r4) {
                const float4 xv = *(const float4*)&xrow[r4 * 4];
                acc[r4 * 4 + 0] = fmaf(xv.x, wv_, acc[r4 * 4 + 0]);
                acc[r4 * 4 + 1] = fmaf(xv.y, wv_, acc[r4 * 4 + 1]);
                acc[r4 * 4 + 2] = fmaf(xv.z, wv_, acc[r4 * 4 + 2]);
                acc[r4 * 4 + 3] = fmaf(xv.w, wv_, acc[r4 * 4 + 3]);
            }
        }
    }

    #pragma unroll
    for (int r = 0; r < 32; ++r) {
        const int n = base + r;
        if (n < n_nodes) {
            const float val = acc[r] + bias;
            if (m == 0)      q[(size_t)n * DIM + oc]        = val;
            else if (m == 1) kv[(size_t)n * 128 + oc]       = val;
            else if (m == 2) kv[(size_t)n * 128 + 64 + oc]  = val;
            else             agg[(size_t)n * DIM + oc]      = val;   // root skip
        }
    }

    // qwe phase: 32 nodes x 32 cols, 4 outputs/thread
    {
        const int j = tid & 31;
        const int r0 = (tid >> 5) * 4;
        float a0 = 0.f, a1 = 0.f, a2 = 0.f, a3 = 0.f;
        #pragma unroll 8
        for (int c = 0; c < DIM; ++c) {
            const float wv_ = lwqe[c * 32 + j];
            const float4 xv = *(const float4*)&lxT[c * 36 + r0];
            a0 = fmaf(xv.x, wv_, a0);
            a1 = fmaf(xv.y, wv_, a1);
            a2 = fmaf(xv.z, wv_, a2);
            a3 = fmaf(xv.w, wv_, a3);
        }
        const float bb = bqe[j];
        const float av[4] = {a0 + bb, a1 + bb, a2 + bb, a3 + bb};
        #pragma unroll
        for (int i = 0; i < 4; ++i) {
            const int n = base + r0 + i;
            if (n < n_nodes) qwe[(size_t)n * DEA + j] = av[i];
        }
    }
}

// ---------------------------------------------------------------------------
// CSR build over dst: histogram -> 3-pass multi-block scan -> scatter
// ---------------------------------------------------------------------------
__global__ __launch_bounds__(256) void hist_kernel(
    const int* __restrict__ dst, int* __restrict__ counts, int n_edges, int n_nodes)
{
    const int eid = blockIdx.x * 256 + threadIdx.x;
    if (eid >= n_edges) return;
    int d = dst[eid];
    d = (d < 0) ? 0 : ((d >= n_nodes) ? n_nodes - 1 : d);
    atomicAdd(&counts[d], 1);
}

// pass1: block b scans counts[b*1024 .. +1024) locally (exclusive) into
// row_ptr; block total into blksum[b].
__global__ __launch_bounds__(256) void scan_pass1_kernel(
    const int* __restrict__ counts, int* __restrict__ row_ptr,
    int* __restrict__ blksum, int n)
{
    const int tid = threadIdx.x;
    const int lane = tid & 63;
    const int base = blockIdx.x * 1024 + tid * 4;
    int c0 = 0, c1 = 0, c2 = 0, c3 = 0;
    if (base + 3 < n) {
        const int4 v = *(const int4*)&counts[base];
        c0 = v.x; c1 = v.y; c2 = v.z; c3 = v.w;
    } else {
        if (base + 0 < n) c0 = counts[base + 0];
        if (base + 1 < n) c1 = counts[base + 1];
        if (base + 2 < n) c2 = counts[base + 2];
        if (base + 3 < n) c3 = counts[base + 3];
    }
    const int tsum = c0 + c1 + c2 + c3;
    int incl = tsum;
    #pragma unroll
    for (int off = 1; off < 64; off <<= 1) {
        const int t = __shfl_up(incl, off, 64);
        if (lane >= off) incl += t;
    }
    __shared__ int wsum[4];
    const int wv = tid >> 6;
    if (lane == 63) wsum[wv] = incl;
    __syncthreads();
    int woff = 0;
    #pragma unroll
    for (int i = 0; i < 4; ++i) if (i < wv) woff += wsum[i];
    const int excl = woff + incl - tsum;
    if (base + 3 < n) {
        int4 o;
        o.x = excl; o.y = excl + c0; o.z = excl + c0 + c1; o.w = excl + c0 + c1 + c2;
        *(int4*)&row_ptr[base] = o;
    } else {
        if (base + 0 < n) row_ptr[base + 0] = excl;
        if (base + 1 < n) row_ptr[base + 1] = excl + c0;
        if (base + 2 < n) row_ptr[base + 2] = excl + c0 + c1;
        if (base + 3 < n) row_ptr[base + 3] = excl + c0 + c1 + c2;
    }
    if (tid == 255) blksum[blockIdx.x] = woff + incl;
}

// pass2: one wave scans block sums -> exclusive blkoff; writes row_ptr[n].
__global__ __launch_bounds__(64) void scan_pass2_kernel(
    const int* __restrict__ blksum, int* __restrict__ blkoff,
    int* __restrict__ row_ptr, int nb, int n)
{
    const int lane = threadIdx.x;
    int carry = 0;
    for (int base = 0; base < nb; base += 64) {
        const int idx = base + lane;
        const int v = (idx < nb) ? blksum[idx] : 0;
        int incl = v;
        #pragma unroll
        for (int off = 1; off < 64; off <<= 1) {
            const int t = __shfl_up(incl, off, 64);
            if (lane >= off) incl += t;
        }
        if (idx < nb) blkoff[idx] = carry + incl - v;
        carry += __shfl(incl, 63, 64);
    }
    if (lane == 0) row_ptr[n] = carry;
}

// pass3: add block offsets; mirror into cursor for the scatter pass.
__global__ __launch_bounds__(256) void scan_pass3_kernel(
    int* __restrict__ row_ptr, int* __restrict__ cursor,
    const int* __restrict__ blkoff, int n)
{
    const int base = blockIdx.x * 1024 + threadIdx.x * 4;
    const int off = blkoff[blockIdx.x];
    if (base + 3 < n) {
        int4 v = *(const int4*)&row_ptr[base];
        v.x += off; v.y += off; v.z += off; v.w += off;
        *(int4*)&row_ptr[base] = v;
        *(int4*)&cursor[base]  = v;
    } else {
        #pragma unroll
        for (int i = 0; i < 4; ++i) {
            if (base + i < n) {
                const int v = row_ptr[base + i] + off;
                row_ptr[base + i] = v;
                cursor[base + i]  = v;
            }
        }
    }
}

__global__ __launch_bounds__(256) void scatter_kernel(
    const int* __restrict__ dst, const int* __restrict__ src,
    int* __restrict__ cursor, int2* __restrict__ pair, int n_edges, int n_nodes)
{
    const int eid = blockIdx.x * 256 + threadIdx.x;
    if (eid >= n_edges) return;
    int d = dst[eid];
    d = (d < 0) ? 0 : ((d >= n_nodes) ? n_nodes - 1 : d);
    int s = src[eid];
    s = (s < 0) ? 0 : ((s >= n_nodes) ? n_nodes - 1 : s);
    const int pos = atomicAdd(&cursor[d], 1);
    pair[pos] = make_int2(eid, s);
}

// ---------------------------------------------------------------------------
// Fused aggregation v3: one wave per dst node; 4 edge-groups x 16 lanes.
//   score = (q.k[src] + qwe.ea)/8 ;  msg = sum p*v[src] ; sea = sum p*ea
//   out   = relu(skip + (msg + sea@We)/l)
// ---------------------------------------------------------------------------
__global__ __launch_bounds__(256) void fused_edge_kernel(
    const float* __restrict__ q, const float* __restrict__ qwe,
    const float* __restrict__ kv, const float* __restrict__ ea,
    const float* __restrict__ we, const float* __restrict__ aggskip,
    const int* __restrict__ row_ptr, const int2* __restrict__ pair,
    float* __restrict__ h_out, int n_nodes)
{
    __shared__ float lw[DEA * DIM];   // 8 KB, row-major [32][64]
    const int tid = threadIdx.x;
    {
        const float4* s4 = (const float4*)we;
        float4* d4 = (float4*)lw;
        d4[tid] = s4[tid];
        d4[tid + 256] = s4[tid + 256];
    }
    __syncthreads();

    const int wave = tid >> 6;
    const int lane = tid & 63;
    const int g = lane >> 4;
    const int j = lane & 15;
    const int node = blockIdx.x * 4 + wave;
    if (node >= n_nodes) return;

    const float4 q4   = *(const float4*)&q[(size_t)node * DIM + j * 4];
    const float2 qwe2 = *(const float2*)&qwe[(size_t)node * DEA + j * 2];
    const int beg = row_ptr[node], end = row_ptr[node + 1];

    float m = -3.0e38f, l = 0.f;
    float4 msg = make_float4(0.f, 0.f, 0.f, 0.f);
    float2 sea = make_float2(0.f, 0.f);

    if (beg < end) {
        int2 pr = pair[(beg + g < end) ? (beg + g) : (end - 1)];
        for (int i0 = beg; i0 < end; i0 += 4) {
            const bool act = (i0 + g) < end;
            const int eid = pr.x;
            const int s   = pr.y;
            const float4* kvp = (const float4*)&kv[(size_t)s * 128];
            const float4 k4 = kvp[j];
            const float4 v4 = kvp[16 + j];
            const float2 ea2 = *(const float2*)&ea[(size_t)eid * DEA + j * 2];
            const int inext = i0 + 4 + g;
            if (inext < end) pr = pair[inext];   // prefetch next group pair

            float t = fmaf(q4.x, k4.x, qwe2.x * ea2.x);
            t = fmaf(q4.y, k4.y, t);
            t = fmaf(q4.z, k4.z, t);
            t = fmaf(q4.w, k4.w, t);
            t = fmaf(qwe2.y, ea2.y, t);
            t += __shfl_xor(t, 1, 64);
            t += __shfl_xor(t, 2, 64);
            t += __shfl_xor(t, 4, 64);
            t += __shfl_xor(t, 8, 64);
            const float score = act ? t * 0.125f : -3.0e38f;

            const float mn = fmaxf(m, score);
            const float p  = act ? __expf(score - mn) : 0.f;
            const float sc = __expf(m - mn);
            l = l * sc + p;
            msg.x = fmaf(p, v4.x, msg.x * sc);
            msg.y = fmaf(p, v4.y, msg.y * sc);
            msg.z = fmaf(p, v4.z, msg.z * sc);
            msg.w = fmaf(p, v4.w, msg.w * sc);
            sea.x = fmaf(p, ea2.x, sea.x * sc);
            sea.y = fmaf(p, ea2.y, sea.y * sc);
            m = mn;
        }
    }

    #pragma unroll
    for (int off = 16; off <= 32; off <<= 1) {
        const float m2 = __shfl_xor(m, off, 64);
        const float l2 = __shfl_xor(l, off, 64);
        float4 msg2;
        msg2.x = __shfl_xor(msg.x, off, 64);
        msg2.y = __shfl_xor(msg.y, off, 64);
        msg2.z = __shfl_xor(msg.z, off, 64);
        msg2.w = __shfl_xor(msg.w, off, 64);
        float2 sea2;
        sea2.x = __shfl_xor(sea.x, off, 64);
        sea2.y = __shfl_xor(sea.y, off, 64);
        const float mn = fmaxf(m, m2);
        const float s1 = __expf(m - mn);
        const float s2 = __expf(m2 - mn);
        l = l * s1 + l2 * s2;
        msg.x = msg.x * s1 + msg2.x * s2;
        msg.y = msg.y * s1 + msg2.y * s2;
        msg.z = msg.z * s1 + msg2.z * s2;
        msg.w = msg.w * s1 + msg2.w * s2;
        sea.x = sea.x * s1 + sea2.x * s2;
        sea.y = sea.y * s1 + sea2.y * s2;
        m = mn;
    }

    const float4* lw4 = (const float4*)lw;
    float4 e4 = make_float4(0.f, 0.f, 0.f, 0.f);
    #pragma unroll
    for (int tt = 0; tt < 16; ++tt) {
        const float sx = __shfl(sea.x, tt, 64);
        const float sy = __shfl(sea.y, tt, 64);
        const float4 w0 = lw4[(2 * tt) * 16 + j];
        const float4 w1 = lw4[(2 * tt + 1) * 16 + j];
        e4.x = fmaf(sx, w0.x, fmaf(sy, w1.x, e4.x));
        e4.y = fmaf(sx, w0.y, fmaf(sy, w1.y, e4.y));
        e4.z = fmaf(sx, w0.z, fmaf(sy, w1.z, e4.z));
        e4.w = fmaf(sx, w0.w, fmaf(sy, w1.w, e4.w));
    }

    if (lane < 16) {
        const float inv = (l > 0.f) ? (1.f / l) : 0.f;
        const float4 sk = *(const float4*)&aggskip[(size_t)node * DIM + j * 4];
        float4 o;
        o.x = fmaxf(fmaf(msg.x + e4.x, inv, sk.x), 0.f);
        o.y = fmaxf(fmaf(msg.y + e4.y, inv, sk.y), 0.f);
        o.z = fmaxf(fmaf(msg.z + e4.z, inv, sk.z), 0.f);
        o.w = fmaxf(fmaf(msg.w + e4.w, inv, sk.w), 0.f);
        *(float4*)&h_out[(size_t)node * DIM + j * 4] = o;
    }
}

// ---------------------------------------------------------------------------
// Final: out = relu(concat(h1,h2) @ skip_w + skip_b), K=128
// ---------------------------------------------------------------------------
__global__ __launch_bounds__(256) void final_kernel(
    const float* __restrict__ h1, const float* __restrict__ h2,
    const float* __restrict__ w, const float* __restrict__ b,
    float* __restrict__ out, int n_nodes)
{
    __shared__ float lw[128 * DIM];   // 32 KB
    __shared__ float lx[16][128];     // 8 KB
    const int tid = threadIdx.x;
    {
        const float4* s4 = (const float4*)w;
        float4* d4 = (float4*)lw;
        #pragma unroll
        for (int i = 0; i < 8; ++i) d4[tid + i * 256] = s4[tid + i * 256];
    }
    const int base = blockIdx.x * 16;
    {
        #pragma unroll
        for (int t = 0; t < 2; ++t) {
            const int f = tid + t * 256;
            const int r = f >> 5;
            const int cf = f & 31;
            const int n = base + r;
            float4 val = make_float4(0.f, 0.f, 0.f, 0.f);
            if (n < n_nodes) {
                if (cf < 16) val = *(const float4*)&h1[(size_t)n * DIM + cf * 4];
                else         val = *(const float4*)&h2[(size_t)n * DIM + (cf - 16) * 4];
            }
            *(float4*)&lx[r][cf * 4] = val;
        }
    }
    __syncthreads();

    const int oc = tid & 63;
    const int nl = tid >> 6;
    float acc[4] = {0, 0, 0, 0};
    #pragma unroll 8
    for (int kk = 0; kk < 128; ++kk) {
        const float wv = lw[kk * DIM + oc];
        #pragma unroll
        for (int r = 0; r < 4; ++r)
            acc[r] = fmaf(lx[nl * 4 + r][kk], wv, acc[r]);
    }
    const float bv = b[oc];
    #pragma unroll
    for (int r = 0; r < 4; ++r) {
        const int n = base + nl * 4 + r;
        if (n < n_nodes) out[(size_t)n * DIM + oc] = fmaxf(acc[r] + bv, 0.f);
    }
}

// ---------------------------------------------------------------------------
extern "C" void kernel_launch(void* const* d_in, const int* in_sizes, int n_in,
                              void* d_out, int out_size, void* d_ws, size_t ws_size,
                              hipStream_t stream)
{
    const float* x     = (const float*)d_in[0];
    const int*   ei    = (const int*)d_in[1];
    const float* eattr = (const float*)d_in[2];
    const float *q1w = (const float*)d_in[3],  *q1b = (const float*)d_in[4];
    const float *k1w = (const float*)d_in[5],  *k1b = (const float*)d_in[6];
    const float *v1w = (const float*)d_in[7],  *v1b = (const float*)d_in[8];
    const float *e1w = (const float*)d_in[9];
    const float *s1w = (const float*)d_in[10], *s1b = (const float*)d_in[11];
    const float *q2w = (const float*)d_in[12], *q2b = (const float*)d_in[13];
    const float *k2w = (const float*)d_in[14], *k2b = (const float*)d_in[15];
    const float *v2w = (const float*)d_in[16], *v2b = (const float*)d_in[17];
    const float *e2w = (const float*)d_in[18];
    const float *s2w = (const float*)d_in[19], *s2b = (const float*)d_in[20];
    const float *skw = (const float*)d_in[21], *skb = (const float*)d_in[22];

    const int N = in_sizes[0] / DIM;
    const int E = in_sizes[1] / 2;
    const int* src = ei;
    const int* dst = ei + E;

    float* ws = (float*)d_ws;
    const size_t nf = (size_t)N * DIM;
    float* q    = ws;             // nf
    float* kv   = q + nf;         // 2*nf
    float* agg  = kv + 2 * nf;    // nf
    float* h1   = agg + nf;       // nf
    float* h2   = h1 + nf;        // nf
    float* qwe  = h2 + nf;        // 32*N
    int2* pair    = (int2*)(qwe + (size_t)DEA * N);    // E int2 (16B-aligned region)
    int* cursor   = (int*)(pair + E);                  // N   (16B aligned: 8E%16==0)
    int* row_ptr  = cursor + ((N + 3) & ~3);           // N+1 (16B aligned)
    const int nb  = (N + 1023) / 1024;
    int* blksum   = row_ptr + ((N + 4) & ~3);          // nb
    int* blkoff   = blksum + ((nb + 3) & ~3);          // nb
    float* wqeW1  = (float*)(blkoff + ((nb + 3) & ~3));// 2048
    float* bqe1   = wqeW1 + 64 * 32;                   // 32
    float* wqeW2  = bqe1 + 32;                         // 2048
    float* bqe2   = wqeW2 + 64 * 32;                   // 32

    const int nblk = (N + 31) / 32;
    const int eblk = (E + 255) / 256;
    const int fblk = (N + 3) / 4;
    const int finblk = (N + 15) / 16;

    // ---------------- CSR over dst + combined score weights ----------------
    hipMemsetAsync(cursor, 0, (size_t)N * sizeof(int), stream);
    hist_kernel<<<eblk, 256, 0, stream>>>(dst, cursor, E, N);
    scan_pass1_kernel<<<nb, 256, 0, stream>>>(cursor, row_ptr, blksum, N);
    scan_pass2_kernel<<<1, 64, 0, stream>>>(blksum, blkoff, row_ptr, nb, N);
    scan_pass3_kernel<<<nb, 256, 0, stream>>>(row_ptr, cursor, blkoff, N);
    scatter_kernel<<<eblk, 256, 0, stream>>>(dst, src, cursor, pair, E, N);
    wqe_prep_kernel<<<2, 256, 0, stream>>>(q1w, q1b, e1w, q2w, q2b, e2w,
                                           wqeW1, bqe1, wqeW2, bqe2);

    // ---------------- layer 1 ----------------
    node_lin_kernel<<<nblk, 256, 0, stream>>>(x, q1w, q1b, k1w, k1b, v1w, v1b,
                                              s1w, s1b, wqeW1, bqe1,
                                              q, kv, agg, qwe, N);
    fused_edge_kernel<<<fblk, 256, 0, stream>>>(q, qwe, kv, eattr, e1w, agg,
                                                row_ptr, pair, h1, N);

    // ---------------- layer 2 ----------------
    node_lin_kernel<<<nblk, 256, 0, stream>>>(h1, q2w, q2b, k2w, k2b, v2w, v2b,
                                              s2w, s2b, wqeW2, bqe2,
                                              q, kv, agg, qwe, N);
    fused_edge_kernel<<<fblk, 256, 0, stream>>>(q, qwe, kv, eattr, e2w, agg,
                                                row_ptr, pair, h2, N);

    // ---------------- final skip MLP ----------------
    final_kernel<<<finblk, 256, 0, stream>>>(h1, h2, skw, skb, (float*)d_out, N);
}

// Round 7
// 360.652 us; speedup vs baseline: 2.4759x; 1.0964x over previous
//
#include <hip/hip_runtime.h>

#define DIM 64
#define DEA 32

__device__ __forceinline__ unsigned short f2bf(float f) {
    const unsigned u = __float_as_uint(f);
    return (unsigned short)((u + 0x7FFFu + ((u >> 16) & 1u)) >> 16);   // RNE
}
__device__ __forceinline__ float bf2f(unsigned short h) {
    return __uint_as_float(((unsigned)h) << 16);
}

// ---------------------------------------------------------------------------
// One-time: combined score weight  M = Wq @ We^T  [64][32],  bqe = bq @ We^T.
// ---------------------------------------------------------------------------
__global__ __launch_bounds__(256) void wqe_prep_kernel(
    const float* __restrict__ wq1, const float* __restrict__ bq1, const float* __restrict__ we1,
    const float* __restrict__ wq2, const float* __restrict__ bq2, const float* __restrict__ we2,
    float* __restrict__ w1out, float* __restrict__ b1out,
    float* __restrict__ w2out, float* __restrict__ b2out)
{
    const float* wq = blockIdx.x ? wq2 : wq1;
    const float* bq = blockIdx.x ? bq2 : bq1;
    const float* we = blockIdx.x ? we2 : we1;
    float* wout = blockIdx.x ? w2out : w1out;
    float* bout = blockIdx.x ? b2out : b1out;

    __shared__ float lq[64 * 64];
    __shared__ float lweT[64 * 33];
    const int tid = threadIdx.x;
    {
        const float4* s4 = (const float4*)wq;
        float4* d4 = (float4*)lq;
        #pragma unroll
        for (int i = 0; i < 4; ++i) d4[tid + i * 256] = s4[tid + i * 256];
        const float4* e4 = (const float4*)we;
        #pragma unroll
        for (int t = 0; t < 2; ++t) {
            const int f = tid + t * 256;
            const int j = f >> 4;
            const int o4 = (f & 15) * 4;
            const float4 v = e4[f];
            lweT[(o4 + 0) * 33 + j] = v.x;
            lweT[(o4 + 1) * 33 + j] = v.y;
            lweT[(o4 + 2) * 33 + j] = v.z;
            lweT[(o4 + 3) * 33 + j] = v.w;
        }
    }
    __syncthreads();
    const int j = tid & 31;
    const int c0 = (tid >> 5) * 8;
    for (int c = c0; c < c0 + 8; ++c) {
        float acc = 0.f;
        #pragma unroll 8
        for (int o = 0; o < 64; ++o) acc = fmaf(lq[c * 64 + o], lweT[o * 33 + j], acc);
        wout[c * 32 + j] = acc;
    }
    if (tid < 32) {
        float acc = 0.f;
        #pragma unroll 8
        for (int o = 0; o < 64; ++o) acc = fmaf(bq[o], lweT[o * 33 + tid], acc);
        bout[tid] = acc;
    }
}

// ---------------------------------------------------------------------------
// Node linear v3: 32 nodes/block; k,v written as bf16 into kvb[N][128].
// ---------------------------------------------------------------------------
__global__ __launch_bounds__(256) void node_lin_kernel(
    const float* __restrict__ x,
    const float* __restrict__ wq, const float* __restrict__ bq,
    const float* __restrict__ wk, const float* __restrict__ bk,
    const float* __restrict__ wv, const float* __restrict__ bv,
    const float* __restrict__ wsk, const float* __restrict__ bsk,
    const float* __restrict__ wqe_w, const float* __restrict__ bqe,
    float* __restrict__ q, unsigned short* __restrict__ kvb,
    float* __restrict__ agg, float* __restrict__ qwe, int n_nodes)
{
    __shared__ float lw[16 * 256];
    __shared__ float lxT[64 * 36];
    __shared__ float lwqe[64 * 32];
    const int tid = threadIdx.x;
    const int base = blockIdx.x * 32;

    {
        #pragma unroll
        for (int t = 0; t < 2; ++t) {
            const int f = tid + t * 256;
            const int node = f >> 4;
            const int c4 = (f & 15) * 4;
            const int n = base + node;
            float4 val = make_float4(0.f, 0.f, 0.f, 0.f);
            if (n < n_nodes) val = *(const float4*)&x[(size_t)n * DIM + c4];
            lxT[(c4 + 0) * 36 + node] = val.x;
            lxT[(c4 + 1) * 36 + node] = val.y;
            lxT[(c4 + 2) * 36 + node] = val.z;
            lxT[(c4 + 3) * 36 + node] = val.w;
        }
        const float4* s4 = (const float4*)wqe_w;
        float4* d4 = (float4*)lwqe;
        d4[tid] = s4[tid];
        d4[tid + 256] = s4[tid + 256];
    }

    const int m = tid >> 6;
    const int oc = tid & 63;
    const float* wsrc = (m == 0) ? wq : (m == 1) ? wk : (m == 2) ? wv : wsk;
    const float bias = ((m == 0) ? bq : (m == 1) ? bk : (m == 2) ? bv : bsk)[oc];

    float acc[32];
    #pragma unroll
    for (int r = 0; r < 32; ++r) acc[r] = 0.f;

    for (int kc = 0; kc < 4; ++kc) {
        __syncthreads();
        #pragma unroll
        for (int i = 0; i < 4; ++i) {
            const int f = oc + i * 64;
            const int kk = f >> 4;
            const int c4 = (f & 15) * 4;
            const float4 w4 = *(const float4*)&wsrc[(size_t)(kc * 16 + kk) * DIM + c4];
            *(float4*)&lw[kk * 256 + m * 64 + c4] = w4;
        }
        __syncthreads();
        #pragma unroll
        for (int kk = 0; kk < 16; ++kk) {
            const float wv_ = lw[kk * 256 + tid];
            const float* xrow = &lxT[(kc * 16 + kk) * 36];
            #pragma unroll
            for (int r4 = 0; r4 < 8; ++r4) {
                const float4 xv = *(const float4*)&xrow[r4 * 4];
                acc[r4 * 4 + 0] = fmaf(xv.x, wv_, acc[r4 * 4 + 0]);
                acc[r4 * 4 + 1] = fmaf(xv.y, wv_, acc[r4 * 4 + 1]);
                acc[r4 * 4 + 2] = fmaf(xv.z, wv_, acc[r4 * 4 + 2]);
                acc[r4 * 4 + 3] = fmaf(xv.w, wv_, acc[r4 * 4 + 3]);
            }
        }
    }

    #pragma unroll
    for (int r = 0; r < 32; ++r) {
        const int n = base + r;
        if (n < n_nodes) {
            const float val = acc[r] + bias;
            if (m == 0)      q[(size_t)n * DIM + oc]            = val;
            else if (m == 1) kvb[(size_t)n * 128 + oc]          = f2bf(val);
            else if (m == 2) kvb[(size_t)n * 128 + 64 + oc]     = f2bf(val);
            else             agg[(size_t)n * DIM + oc]          = val;   // root skip
        }
    }

    // qwe phase
    {
        const int j = tid & 31;
        const int r0 = (tid >> 5) * 4;
        float a0 = 0.f, a1 = 0.f, a2 = 0.f, a3 = 0.f;
        #pragma unroll 8
        for (int c = 0; c < DIM; ++c) {
            const float wv_ = lwqe[c * 32 + j];
            const float4 xv = *(const float4*)&lxT[c * 36 + r0];
            a0 = fmaf(xv.x, wv_, a0);
            a1 = fmaf(xv.y, wv_, a1);
            a2 = fmaf(xv.z, wv_, a2);
            a3 = fmaf(xv.w, wv_, a3);
        }
        const float bb = bqe[j];
        const float av[4] = {a0 + bb, a1 + bb, a2 + bb, a3 + bb};
        #pragma unroll
        for (int i = 0; i < 4; ++i) {
            const int n = base + r0 + i;
            if (n < n_nodes) qwe[(size_t)n * DEA + j] = av[i];
        }
    }
}

// ---------------------------------------------------------------------------
// CSR build over dst: histogram -> 3-pass multi-block scan -> scatter
// ---------------------------------------------------------------------------
__global__ __launch_bounds__(256) void hist_kernel(
    const int* __restrict__ dst, int* __restrict__ counts, int n_edges, int n_nodes)
{
    const int eid = blockIdx.x * 256 + threadIdx.x;
    if (eid >= n_edges) return;
    int d = dst[eid];
    d = (d < 0) ? 0 : ((d >= n_nodes) ? n_nodes - 1 : d);
    atomicAdd(&counts[d], 1);
}

__global__ __launch_bounds__(256) void scan_pass1_kernel(
    const int* __restrict__ counts, int* __restrict__ row_ptr,
    int* __restrict__ blksum, int n)
{
    const int tid = threadIdx.x;
    const int lane = tid & 63;
    const int base = blockIdx.x * 1024 + tid * 4;
    int c0 = 0, c1 = 0, c2 = 0, c3 = 0;
    if (base + 3 < n) {
        const int4 v = *(const int4*)&counts[base];
        c0 = v.x; c1 = v.y; c2 = v.z; c3 = v.w;
    } else {
        if (base + 0 < n) c0 = counts[base + 0];
        if (base + 1 < n) c1 = counts[base + 1];
        if (base + 2 < n) c2 = counts[base + 2];
        if (base + 3 < n) c3 = counts[base + 3];
    }
    const int tsum = c0 + c1 + c2 + c3;
    int incl = tsum;
    #pragma unroll
    for (int off = 1; off < 64; off <<= 1) {
        const int t = __shfl_up(incl, off, 64);
        if (lane >= off) incl += t;
    }
    __shared__ int wsum[4];
    const int wv = tid >> 6;
    if (lane == 63) wsum[wv] = incl;
    __syncthreads();
    int woff = 0;
    #pragma unroll
    for (int i = 0; i < 4; ++i) if (i < wv) woff += wsum[i];
    const int excl = woff + incl - tsum;
    if (base + 3 < n) {
        int4 o;
        o.x = excl; o.y = excl + c0; o.z = excl + c0 + c1; o.w = excl + c0 + c1 + c2;
        *(int4*)&row_ptr[base] = o;
    } else {
        if (base + 0 < n) row_ptr[base + 0] = excl;
        if (base + 1 < n) row_ptr[base + 1] = excl + c0;
        if (base + 2 < n) row_ptr[base + 2] = excl + c0 + c1;
        if (base + 3 < n) row_ptr[base + 3] = excl + c0 + c1 + c2;
    }
    if (tid == 255) blksum[blockIdx.x] = woff + incl;
}

__global__ __launch_bounds__(64) void scan_pass2_kernel(
    const int* __restrict__ blksum, int* __restrict__ blkoff,
    int* __restrict__ row_ptr, int nb, int n)
{
    const int lane = threadIdx.x;
    int carry = 0;
    for (int base = 0; base < nb; base += 64) {
        const int idx = base + lane;
        const int v = (idx < nb) ? blksum[idx] : 0;
        int incl = v;
        #pragma unroll
        for (int off = 1; off < 64; off <<= 1) {
            const int t = __shfl_up(incl, off, 64);
            if (lane >= off) incl += t;
        }
        if (idx < nb) blkoff[idx] = carry + incl - v;
        carry += __shfl(incl, 63, 64);
    }
    if (lane == 0) row_ptr[n] = carry;
}

__global__ __launch_bounds__(256) void scan_pass3_kernel(
    int* __restrict__ row_ptr, int* __restrict__ cursor,
    const int* __restrict__ blkoff, int n)
{
    const int base = blockIdx.x * 1024 + threadIdx.x * 4;
    const int off = blkoff[blockIdx.x];
    if (base + 3 < n) {
        int4 v = *(const int4*)&row_ptr[base];
        v.x += off; v.y += off; v.z += off; v.w += off;
        *(int4*)&row_ptr[base] = v;
        *(int4*)&cursor[base]  = v;
    } else {
        #pragma unroll
        for (int i = 0; i < 4; ++i) {
            if (base + i < n) {
                const int v = row_ptr[base + i] + off;
                row_ptr[base + i] = v;
                cursor[base + i]  = v;
            }
        }
    }
}

__global__ __launch_bounds__(256) void scatter_kernel(
    const int* __restrict__ dst, const int* __restrict__ src,
    int* __restrict__ cursor, int2* __restrict__ pair, int n_edges, int n_nodes)
{
    const int eid = blockIdx.x * 256 + threadIdx.x;
    if (eid >= n_edges) return;
    int d = dst[eid];
    d = (d < 0) ? 0 : ((d >= n_nodes) ? n_nodes - 1 : d);
    int s = src[eid];
    s = (s < 0) ? 0 : ((s >= n_nodes) ? n_nodes - 1 : s);
    const int pos = atomicAdd(&cursor[d], 1);
    pair[pos] = make_int2(eid, s);
}

// ---------------------------------------------------------------------------
// Fused aggregation v4: one wave per dst node; 4 edge-groups x 16 lanes.
// k/v gathered as bf16 (256B/edge instead of 512B).
//   score = (q.k[src] + qwe.ea)/8 ;  msg = sum p*v[src] ; sea = sum p*ea
//   out   = relu(skip + (msg + sea@We)/l)
// ---------------------------------------------------------------------------
__global__ __launch_bounds__(256) void fused_edge_kernel(
    const float* __restrict__ q, const float* __restrict__ qwe,
    const unsigned short* __restrict__ kvb, const float* __restrict__ ea,
    const float* __restrict__ we, const float* __restrict__ aggskip,
    const int* __restrict__ row_ptr, const int2* __restrict__ pair,
    float* __restrict__ h_out, int n_nodes)
{
    __shared__ float lw[DEA * DIM];   // 8 KB, row-major [32][64]
    const int tid = threadIdx.x;
    {
        const float4* s4 = (const float4*)we;
        float4* d4 = (float4*)lw;
        d4[tid] = s4[tid];
        d4[tid + 256] = s4[tid + 256];
    }
    __syncthreads();

    const int wave = tid >> 6;
    const int lane = tid & 63;
    const int g = lane >> 4;
    const int j = lane & 15;
    const int node = blockIdx.x * 4 + wave;
    if (node >= n_nodes) return;

    const float4 q4   = *(const float4*)&q[(size_t)node * DIM + j * 4];
    const float2 qwe2 = *(const float2*)&qwe[(size_t)node * DEA + j * 2];
    const int beg = row_ptr[node], end = row_ptr[node + 1];

    float m = -3.0e38f, l = 0.f;
    float4 msg = make_float4(0.f, 0.f, 0.f, 0.f);
    float2 sea = make_float2(0.f, 0.f);

    if (beg < end) {
        int2 pr = pair[(beg + g < end) ? (beg + g) : (end - 1)];
        for (int i0 = beg; i0 < end; i0 += 4) {
            const bool act = (i0 + g) < end;
            const int eid = pr.x;
            const int s   = pr.y;
            const unsigned short* kvp = &kvb[(size_t)s * 128];
            const ushort4 kraw = *(const ushort4*)&kvp[j * 4];
            const ushort4 vraw = *(const ushort4*)&kvp[64 + j * 4];
            const float2 ea2 = *(const float2*)&ea[(size_t)eid * DEA + j * 2];
            const int inext = i0 + 4 + g;
            if (inext < end) pr = pair[inext];   // prefetch next group pair

            const float4 k4 = make_float4(bf2f(kraw.x), bf2f(kraw.y), bf2f(kraw.z), bf2f(kraw.w));
            const float4 v4 = make_float4(bf2f(vraw.x), bf2f(vraw.y), bf2f(vraw.z), bf2f(vraw.w));

            float t = fmaf(q4.x, k4.x, qwe2.x * ea2.x);
            t = fmaf(q4.y, k4.y, t);
            t = fmaf(q4.z, k4.z, t);
            t = fmaf(q4.w, k4.w, t);
            t = fmaf(qwe2.y, ea2.y, t);
            t += __shfl_xor(t, 1, 64);
            t += __shfl_xor(t, 2, 64);
            t += __shfl_xor(t, 4, 64);
            t += __shfl_xor(t, 8, 64);
            const float score = act ? t * 0.125f : -3.0e38f;

            const float mn = fmaxf(m, score);
            const float p  = act ? __expf(score - mn) : 0.f;
            const float sc = __expf(m - mn);
            l = l * sc + p;
            msg.x = fmaf(p, v4.x, msg.x * sc);
            msg.y = fmaf(p, v4.y, msg.y * sc);
            msg.z = fmaf(p, v4.z, msg.z * sc);
            msg.w = fmaf(p, v4.w, msg.w * sc);
            sea.x = fmaf(p, ea2.x, sea.x * sc);
            sea.y = fmaf(p, ea2.y, sea.y * sc);
            m = mn;
        }
    }

    #pragma unroll
    for (int off = 16; off <= 32; off <<= 1) {
        const float m2 = __shfl_xor(m, off, 64);
        const float l2 = __shfl_xor(l, off, 64);
        float4 msg2;
        msg2.x = __shfl_xor(msg.x, off, 64);
        msg2.y = __shfl_xor(msg.y, off, 64);
        msg2.z = __shfl_xor(msg.z, off, 64);
        msg2.w = __shfl_xor(msg.w, off, 64);
        float2 sea2;
        sea2.x = __shfl_xor(sea.x, off, 64);
        sea2.y = __shfl_xor(sea.y, off, 64);
        const float mn = fmaxf(m, m2);
        const float s1 = __expf(m - mn);
        const float s2 = __expf(m2 - mn);
        l = l * s1 + l2 * s2;
        msg.x = msg.x * s1 + msg2.x * s2;
        msg.y = msg.y * s1 + msg2.y * s2;
        msg.z = msg.z * s1 + msg2.z * s2;
        msg.w = msg.w * s1 + msg2.w * s2;
        sea.x = sea.x * s1 + sea2.x * s2;
        sea.y = sea.y * s1 + sea2.y * s2;
        m = mn;
    }

    const float4* lw4 = (const float4*)lw;
    float4 e4 = make_float4(0.f, 0.f, 0.f, 0.f);
    #pragma unroll
    for (int tt = 0; tt < 16; ++tt) {
        const float sx = __shfl(sea.x, tt, 64);
        const float sy = __shfl(sea.y, tt, 64);
        const float4 w0 = lw4[(2 * tt) * 16 + j];
        const float4 w1 = lw4[(2 * tt + 1) * 16 + j];
        e4.x = fmaf(sx, w0.x, fmaf(sy, w1.x, e4.x));
        e4.y = fmaf(sx, w0.y, fmaf(sy, w1.y, e4.y));
        e4.z = fmaf(sx, w0.z, fmaf(sy, w1.z, e4.z));
        e4.w = fmaf(sx, w0.w, fmaf(sy, w1.w, e4.w));
    }

    if (lane < 16) {
        const float inv = (l > 0.f) ? (1.f / l) : 0.f;
        const float4 sk = *(const float4*)&aggskip[(size_t)node * DIM + j * 4];
        float4 o;
        o.x = fmaxf(fmaf(msg.x + e4.x, inv, sk.x), 0.f);
        o.y = fmaxf(fmaf(msg.y + e4.y, inv, sk.y), 0.f);
        o.z = fmaxf(fmaf(msg.z + e4.z, inv, sk.z), 0.f);
        o.w = fmaxf(fmaf(msg.w + e4.w, inv, sk.w), 0.f);
        *(float4*)&h_out[(size_t)node * DIM + j * 4] = o;
    }
}

// ---------------------------------------------------------------------------
// Final: out = relu(concat(h1,h2) @ skip_w + skip_b), K=128
// ---------------------------------------------------------------------------
__global__ __launch_bounds__(256) void final_kernel(
    const float* __restrict__ h1, const float* __restrict__ h2,
    const float* __restrict__ w, const float* __restrict__ b,
    float* __restrict__ out, int n_nodes)
{
    __shared__ float lw[128 * DIM];   // 32 KB
    __shared__ float lx[16][128];     // 8 KB
    const int tid = threadIdx.x;
    {
        const float4* s4 = (const float4*)w;
        float4* d4 = (float4*)lw;
        #pragma unroll
        for (int i = 0; i < 8; ++i) d4[tid + i * 256] = s4[tid + i * 256];
    }
    const int base = blockIdx.x * 16;
    {
        #pragma unroll
        for (int t = 0; t < 2; ++t) {
            const int f = tid + t * 256;
            const int r = f >> 5;
            const int cf = f & 31;
            const int n = base + r;
            float4 val = make_float4(0.f, 0.f, 0.f, 0.f);
            if (n < n_nodes) {
                if (cf < 16) val = *(const float4*)&h1[(size_t)n * DIM + cf * 4];
                else         val = *(const float4*)&h2[(size_t)n * DIM + (cf - 16) * 4];
            }
            *(float4*)&lx[r][cf * 4] = val;
        }
    }
    __syncthreads();

    const int oc = tid & 63;
    const int nl = tid >> 6;
    float acc[4] = {0, 0, 0, 0};
    #pragma unroll 8
    for (int kk = 0; kk < 128; ++kk) {
        const float wv = lw[kk * DIM + oc];
        #pragma unroll
        for (int r = 0; r < 4; ++r)
            acc[r] = fmaf(lx[nl * 4 + r][kk], wv, acc[r]);
    }
    const float bv = b[oc];
    #pragma unroll
    for (int r = 0; r < 4; ++r) {
        const int n = base + nl * 4 + r;
        if (n < n_nodes) out[(size_t)n * DIM + oc] = fmaxf(acc[r] + bv, 0.f);
    }
}

// ---------------------------------------------------------------------------
extern "C" void kernel_launch(void* const* d_in, const int* in_sizes, int n_in,
                              void* d_out, int out_size, void* d_ws, size_t ws_size,
                              hipStream_t stream)
{
    const float* x     = (const float*)d_in[0];
    const int*   ei    = (const int*)d_in[1];
    const float* eattr = (const float*)d_in[2];
    const float *q1w = (const float*)d_in[3],  *q1b = (const float*)d_in[4];
    const float *k1w = (const float*)d_in[5],  *k1b = (const float*)d_in[6];
    const float *v1w = (const float*)d_in[7],  *v1b = (const float*)d_in[8];
    const float *e1w = (const float*)d_in[9];
    const float *s1w = (const float*)d_in[10], *s1b = (const float*)d_in[11];
    const float *q2w = (const float*)d_in[12], *q2b = (const float*)d_in[13];
    const float *k2w = (const float*)d_in[14], *k2b = (const float*)d_in[15];
    const float *v2w = (const float*)d_in[16], *v2b = (const float*)d_in[17];
    const float *e2w = (const float*)d_in[18];
    const float *s2w = (const float*)d_in[19], *s2b = (const float*)d_in[20];
    const float *skw = (const float*)d_in[21], *skb = (const float*)d_in[22];

    const int N = in_sizes[0] / DIM;
    const int E = in_sizes[1] / 2;
    const int* src = ei;
    const int* dst = ei + E;

    float* ws = (float*)d_ws;
    const size_t nf = (size_t)N * DIM;
    float* q    = ws;                          // nf
    unsigned short* kvb = (unsigned short*)(q + nf);  // N*128 ushorts = nf floats
    float* agg  = q + 2 * nf;                  // nf
    float* h1   = agg + nf;                    // nf
    float* h2   = h1 + nf;                     // nf
    float* qwe  = h2 + nf;                     // 32*N
    int2* pair    = (int2*)(qwe + (size_t)DEA * N);    // E int2
    int* cursor   = (int*)(pair + E);                  // N
    int* row_ptr  = cursor + ((N + 3) & ~3);           // N+1
    const int nb  = (N + 1023) / 1024;
    int* blksum   = row_ptr + ((N + 4) & ~3);          // nb
    int* blkoff   = blksum + ((nb + 3) & ~3);          // nb
    float* wqeW1  = (float*)(blkoff + ((nb + 3) & ~3));// 2048
    float* bqe1   = wqeW1 + 64 * 32;                   // 32
    float* wqeW2  = bqe1 + 32;                         // 2048
    float* bqe2   = wqeW2 + 64 * 32;                   // 32

    const int nblk = (N + 31) / 32;
    const int eblk = (E + 255) / 256;
    const int fblk = (N + 3) / 4;
    const int finblk = (N + 15) / 16;

    // ---------------- CSR over dst + combined score weights ----------------
    hipMemsetAsync(cursor, 0, (size_t)N * sizeof(int), stream);
    hist_kernel<<<eblk, 256, 0, stream>>>(dst, cursor, E, N);
    scan_pass1_kernel<<<nb, 256, 0, stream>>>(cursor, row_ptr, blksum, N);
    scan_pass2_kernel<<<1, 64, 0, stream>>>(blksum, blkoff, row_ptr, nb, N);
    scan_pass3_kernel<<<nb, 256, 0, stream>>>(row_ptr, cursor, blkoff, N);
    scatter_kernel<<<eblk, 256, 0, stream>>>(dst, src, cursor, pair, E, N);
    wqe_prep_kernel<<<2, 256, 0, stream>>>(q1w, q1b, e1w, q2w, q2b, e2w,
                                           wqeW1, bqe1, wqeW2, bqe2);

    // ---------------- layer 1 ----------------
    node_lin_kernel<<<nblk, 256, 0, stream>>>(x, q1w, q1b, k1w, k1b, v1w, v1b,
                                              s1w, s1b, wqeW1, bqe1,
                                              q, kvb, agg, qwe, N);
    fused_edge_kernel<<<fblk, 256, 0, stream>>>(q, qwe, kvb, eattr, e1w, agg,
                                                row_ptr, pair, h1, N);

    // ---------------- layer 2 ----------------
    node_lin_kernel<<<nblk, 256, 0, stream>>>(h1, q2w, q2b, k2w, k2b, v2w, v2b,
                                              s2w, s2b, wqeW2, bqe2,
                                              q, kvb, agg, qwe, N);
    fused_edge_kernel<<<fblk, 256, 0, stream>>>(q, qwe, kvb, eattr, e2w, agg,
                                                row_ptr, pair, h2, N);

    // ---------------- final skip MLP ----------------
    final_kernel<<<finblk, 256, 0, stream>>>(h1, h2, skw, skb, (float*)d_out, N);
}

// Round 8
// 341.672 us; speedup vs baseline: 2.6134x; 1.0556x over previous
//
#include <hip/hip_runtime.h>

#define DIM 64
#define DEA 32

__device__ __forceinline__ unsigned short f2bf(float f) {
    const unsigned u = __float_as_uint(f);
    return (unsigned short)((u + 0x7FFFu + ((u >> 16) & 1u)) >> 16);   // RNE
}
__device__ __forceinline__ float bflo(unsigned u) { return __uint_as_float(u << 16); }
__device__ __forceinline__ float bfhi(unsigned u) { return __uint_as_float(u & 0xFFFF0000u); }

// ---------------------------------------------------------------------------
// One-time: combined score weight  M = (Wq @ We^T)*0.125  [64][32],
// bqe = (bq @ We^T)*0.125.  (score scale folded in; exact pow2)
// ---------------------------------------------------------------------------
__global__ __launch_bounds__(256) void wqe_prep_kernel(
    const float* __restrict__ wq1, const float* __restrict__ bq1, const float* __restrict__ we1,
    const float* __restrict__ wq2, const float* __restrict__ bq2, const float* __restrict__ we2,
    float* __restrict__ w1out, float* __restrict__ b1out,
    float* __restrict__ w2out, float* __restrict__ b2out)
{
    const float* wq = blockIdx.x ? wq2 : wq1;
    const float* bq = blockIdx.x ? bq2 : bq1;
    const float* we = blockIdx.x ? we2 : we1;
    float* wout = blockIdx.x ? w2out : w1out;
    float* bout = blockIdx.x ? b2out : b1out;

    __shared__ float lq[64 * 64];
    __shared__ float lweT[64 * 33];
    const int tid = threadIdx.x;
    {
        const float4* s4 = (const float4*)wq;
        float4* d4 = (float4*)lq;
        #pragma unroll
        for (int i = 0; i < 4; ++i) d4[tid + i * 256] = s4[tid + i * 256];
        const float4* e4 = (const float4*)we;
        #pragma unroll
        for (int t = 0; t < 2; ++t) {
            const int f = tid + t * 256;
            const int j = f >> 4;
            const int o4 = (f & 15) * 4;
            const float4 v = e4[f];
            lweT[(o4 + 0) * 33 + j] = v.x;
            lweT[(o4 + 1) * 33 + j] = v.y;
            lweT[(o4 + 2) * 33 + j] = v.z;
            lweT[(o4 + 3) * 33 + j] = v.w;
        }
    }
    __syncthreads();
    const int j = tid & 31;
    const int c0 = (tid >> 5) * 8;
    for (int c = c0; c < c0 + 8; ++c) {
        float acc = 0.f;
        #pragma unroll 8
        for (int o = 0; o < 64; ++o) acc = fmaf(lq[c * 64 + o], lweT[o * 33 + j], acc);
        wout[c * 32 + j] = acc * 0.125f;
    }
    if (tid < 32) {
        float acc = 0.f;
        #pragma unroll 8
        for (int o = 0; o < 64; ++o) acc = fmaf(bq[o], lweT[o * 33 + tid], acc);
        bout[tid] = acc * 0.125f;
    }
}

// ---------------------------------------------------------------------------
// Node linear v3: 32 nodes/block; q scaled by 0.125; k,v as bf16.
// ---------------------------------------------------------------------------
__global__ __launch_bounds__(256) void node_lin_kernel(
    const float* __restrict__ x,
    const float* __restrict__ wq, const float* __restrict__ bq,
    const float* __restrict__ wk, const float* __restrict__ bk,
    const float* __restrict__ wv, const float* __restrict__ bv,
    const float* __restrict__ wsk, const float* __restrict__ bsk,
    const float* __restrict__ wqe_w, const float* __restrict__ bqe,
    float* __restrict__ q, unsigned short* __restrict__ kvb,
    float* __restrict__ agg, float* __restrict__ qwe, int n_nodes)
{
    __shared__ float lw[16 * 256];
    __shared__ float lxT[64 * 36];
    __shared__ float lwqe[64 * 32];
    const int tid = threadIdx.x;
    const int base = blockIdx.x * 32;

    {
        #pragma unroll
        for (int t = 0; t < 2; ++t) {
            const int f = tid + t * 256;
            const int node = f >> 4;
            const int c4 = (f & 15) * 4;
            const int n = base + node;
            float4 val = make_float4(0.f, 0.f, 0.f, 0.f);
            if (n < n_nodes) val = *(const float4*)&x[(size_t)n * DIM + c4];
            lxT[(c4 + 0) * 36 + node] = val.x;
            lxT[(c4 + 1) * 36 + node] = val.y;
            lxT[(c4 + 2) * 36 + node] = val.z;
            lxT[(c4 + 3) * 36 + node] = val.w;
        }
        const float4* s4 = (const float4*)wqe_w;
        float4* d4 = (float4*)lwqe;
        d4[tid] = s4[tid];
        d4[tid + 256] = s4[tid + 256];
    }

    const int m = tid >> 6;
    const int oc = tid & 63;
    const float* wsrc = (m == 0) ? wq : (m == 1) ? wk : (m == 2) ? wv : wsk;
    const float bias = ((m == 0) ? bq : (m == 1) ? bk : (m == 2) ? bv : bsk)[oc];

    float acc[32];
    #pragma unroll
    for (int r = 0; r < 32; ++r) acc[r] = 0.f;

    for (int kc = 0; kc < 4; ++kc) {
        __syncthreads();
        #pragma unroll
        for (int i = 0; i < 4; ++i) {
            const int f = oc + i * 64;
            const int kk = f >> 4;
            const int c4 = (f & 15) * 4;
            const float4 w4 = *(const float4*)&wsrc[(size_t)(kc * 16 + kk) * DIM + c4];
            *(float4*)&lw[kk * 256 + m * 64 + c4] = w4;
        }
        __syncthreads();
        #pragma unroll
        for (int kk = 0; kk < 16; ++kk) {
            const float wv_ = lw[kk * 256 + tid];
            const float* xrow = &lxT[(kc * 16 + kk) * 36];
            #pragma unroll
            for (int r4 = 0; r4 < 8; ++r4) {
                const float4 xv = *(const float4*)&xrow[r4 * 4];
                acc[r4 * 4 + 0] = fmaf(xv.x, wv_, acc[r4 * 4 + 0]);
                acc[r4 * 4 + 1] = fmaf(xv.y, wv_, acc[r4 * 4 + 1]);
                acc[r4 * 4 + 2] = fmaf(xv.z, wv_, acc[r4 * 4 + 2]);
                acc[r4 * 4 + 3] = fmaf(xv.w, wv_, acc[r4 * 4 + 3]);
            }
        }
    }

    #pragma unroll
    for (int r = 0; r < 32; ++r) {
        const int n = base + r;
        if (n < n_nodes) {
            const float val = acc[r] + bias;
            if (m == 0)      q[(size_t)n * DIM + oc]            = val * 0.125f;
            else if (m == 1) kvb[(size_t)n * 128 + oc]          = f2bf(val);
            else if (m == 2) kvb[(size_t)n * 128 + 64 + oc]     = f2bf(val);
            else             agg[(size_t)n * DIM + oc]          = val;   // root skip
        }
    }

    // qwe phase (weights pre-scaled by 0.125)
    {
        const int j = tid & 31;
        const int r0 = (tid >> 5) * 4;
        float a0 = 0.f, a1 = 0.f, a2 = 0.f, a3 = 0.f;
        #pragma unroll 8
        for (int c = 0; c < DIM; ++c) {
            const float wv_ = lwqe[c * 32 + j];
            const float4 xv = *(const float4*)&lxT[c * 36 + r0];
            a0 = fmaf(xv.x, wv_, a0);
            a1 = fmaf(xv.y, wv_, a1);
            a2 = fmaf(xv.z, wv_, a2);
            a3 = fmaf(xv.w, wv_, a3);
        }
        const float bb = bqe[j];
        const float av[4] = {a0 + bb, a1 + bb, a2 + bb, a3 + bb};
        #pragma unroll
        for (int i = 0; i < 4; ++i) {
            const int n = base + r0 + i;
            if (n < n_nodes) qwe[(size_t)n * DEA + j] = av[i];
        }
    }
}

// ---------------------------------------------------------------------------
// CSR build over dst: histogram -> 3-pass multi-block scan -> scatter
// ---------------------------------------------------------------------------
__global__ __launch_bounds__(256) void hist_kernel(
    const int* __restrict__ dst, int* __restrict__ counts, int n_edges, int n_nodes)
{
    const int eid = blockIdx.x * 256 + threadIdx.x;
    if (eid >= n_edges) return;
    int d = dst[eid];
    d = (d < 0) ? 0 : ((d >= n_nodes) ? n_nodes - 1 : d);
    atomicAdd(&counts[d], 1);
}

__global__ __launch_bounds__(256) void scan_pass1_kernel(
    const int* __restrict__ counts, int* __restrict__ row_ptr,
    int* __restrict__ blksum, int n)
{
    const int tid = threadIdx.x;
    const int lane = tid & 63;
    const int base = blockIdx.x * 1024 + tid * 4;
    int c0 = 0, c1 = 0, c2 = 0, c3 = 0;
    if (base + 3 < n) {
        const int4 v = *(const int4*)&counts[base];
        c0 = v.x; c1 = v.y; c2 = v.z; c3 = v.w;
    } else {
        if (base + 0 < n) c0 = counts[base + 0];
        if (base + 1 < n) c1 = counts[base + 1];
        if (base + 2 < n) c2 = counts[base + 2];
        if (base + 3 < n) c3 = counts[base + 3];
    }
    const int tsum = c0 + c1 + c2 + c3;
    int incl = tsum;
    #pragma unroll
    for (int off = 1; off < 64; off <<= 1) {
        const int t = __shfl_up(incl, off, 64);
        if (lane >= off) incl += t;
    }
    __shared__ int wsum[4];
    const int wv = tid >> 6;
    if (lane == 63) wsum[wv] = incl;
    __syncthreads();
    int woff = 0;
    #pragma unroll
    for (int i = 0; i < 4; ++i) if (i < wv) woff += wsum[i];
    const int excl = woff + incl - tsum;
    if (base + 3 < n) {
        int4 o;
        o.x = excl; o.y = excl + c0; o.z = excl + c0 + c1; o.w = excl + c0 + c1 + c2;
        *(int4*)&row_ptr[base] = o;
    } else {
        if (base + 0 < n) row_ptr[base + 0] = excl;
        if (base + 1 < n) row_ptr[base + 1] = excl + c0;
        if (base + 2 < n) row_ptr[base + 2] = excl + c0 + c1;
        if (base + 3 < n) row_ptr[base + 3] = excl + c0 + c1 + c2;
    }
    if (tid == 255) blksum[blockIdx.x] = woff + incl;
}

__global__ __launch_bounds__(64) void scan_pass2_kernel(
    const int* __restrict__ blksum, int* __restrict__ blkoff,
    int* __restrict__ row_ptr, int nb, int n)
{
    const int lane = threadIdx.x;
    int carry = 0;
    for (int base = 0; base < nb; base += 64) {
        const int idx = base + lane;
        const int v = (idx < nb) ? blksum[idx] : 0;
        int incl = v;
        #pragma unroll
        for (int off = 1; off < 64; off <<= 1) {
            const int t = __shfl_up(incl, off, 64);
            if (lane >= off) incl += t;
        }
        if (idx < nb) blkoff[idx] = carry + incl - v;
        carry += __shfl(incl, 63, 64);
    }
    if (lane == 0) row_ptr[n] = carry;
}

__global__ __launch_bounds__(256) void scan_pass3_kernel(
    int* __restrict__ row_ptr, int* __restrict__ cursor,
    const int* __restrict__ blkoff, int n)
{
    const int base = blockIdx.x * 1024 + threadIdx.x * 4;
    const int off = blkoff[blockIdx.x];
    if (base + 3 < n) {
        int4 v = *(const int4*)&row_ptr[base];
        v.x += off; v.y += off; v.z += off; v.w += off;
        *(int4*)&row_ptr[base] = v;
        *(int4*)&cursor[base]  = v;
    } else {
        #pragma unroll
        for (int i = 0; i < 4; ++i) {
            if (base + i < n) {
                const int v = row_ptr[base + i] + off;
                row_ptr[base + i] = v;
                cursor[base + i]  = v;
            }
        }
    }
}

__global__ __launch_bounds__(256) void scatter_kernel(
    const int* __restrict__ dst, const int* __restrict__ src,
    int* __restrict__ cursor, int2* __restrict__ pair, int n_edges, int n_nodes)
{
    const int eid = blockIdx.x * 256 + threadIdx.x;
    if (eid >= n_edges) return;
    int d = dst[eid];
    d = (d < 0) ? 0 : ((d >= n_nodes) ? n_nodes - 1 : d);
    int s = src[eid];
    s = (s < 0) ? 0 : ((s >= n_nodes) ? n_nodes - 1 : s);
    const int pos = atomicAdd(&cursor[d], 1);
    pair[pos] = make_int2(eid, s);
}

// ---------------------------------------------------------------------------
// Fused aggregation v5: one wave per dst node; 8 edge-groups x 8 lanes.
// Lane owns 8 channels (k,v as one ushort8 each) + 4 ea/qwe slots (float4).
// Scale 0.125 pre-folded into q and qwe.
//   score = q.k[src] + qwe.ea ;  msg = sum p*v[src] ; sea = sum p*ea
//   out   = relu(skip + (msg + sea@We)/l)   (epilogue all-lane via LDS)
// ---------------------------------------------------------------------------
__global__ __launch_bounds__(256) void fused_edge_kernel(
    const float* __restrict__ q, const float* __restrict__ qwe,
    const unsigned short* __restrict__ kvb, const float* __restrict__ ea,
    const float* __restrict__ we, const float* __restrict__ aggskip,
    const int* __restrict__ row_ptr, const int2* __restrict__ pair,
    float* __restrict__ h_out, int n_nodes)
{
    __shared__ float lw[DEA * DIM];   // 8 KB, We row-major [32][64]
    __shared__ float lsea[4][36];     // per-wave merged sea
    __shared__ float lmsg[4][72];     // per-wave merged msg
    const int tid = threadIdx.x;
    {
        const float4* s4 = (const float4*)we;
        float4* d4 = (float4*)lw;
        d4[tid] = s4[tid];
        d4[tid + 256] = s4[tid + 256];
    }
    __syncthreads();

    const int wave = tid >> 6;
    const int lane = tid & 63;
    const int g = lane >> 3;          // edge group 0..7
    const int j = lane & 7;           // channel slot: ch [j*8, j*8+8)
    const int node = blockIdx.x * 4 + wave;
    if (node >= n_nodes) return;

    const float4 qa  = *(const float4*)&q[(size_t)node * DIM + j * 8];
    const float4 qb  = *(const float4*)&q[(size_t)node * DIM + j * 8 + 4];
    const float4 qw4 = *(const float4*)&qwe[(size_t)node * DEA + j * 4];
    const int beg = row_ptr[node], end = row_ptr[node + 1];

    float m = -3.0e38f, l = 0.f;
    float4 msgA = make_float4(0.f, 0.f, 0.f, 0.f);
    float4 msgB = make_float4(0.f, 0.f, 0.f, 0.f);
    float4 sea  = make_float4(0.f, 0.f, 0.f, 0.f);

    if (beg < end) {
        int2 pr = pair[(beg + g < end) ? (beg + g) : (end - 1)];
        for (int i0 = beg; i0 < end; i0 += 8) {
            const bool act = (i0 + g) < end;
            const int eid = pr.x;
            const int s   = pr.y;
            const unsigned short* kvp = &kvb[(size_t)s * 128];
            const uint4 kraw = *(const uint4*)&kvp[j * 8];         // 8 bf16 k
            const uint4 vraw = *(const uint4*)&kvp[64 + j * 8];    // 8 bf16 v
            const float4 ea4 = *(const float4*)&ea[(size_t)eid * DEA + j * 4];
            const int inext = i0 + 8 + g;
            if (inext < end) pr = pair[inext];   // prefetch next group pair

            float t0 = fmaf(qa.x, bflo(kraw.x), qw4.x * ea4.x);
            t0 = fmaf(qa.y, bfhi(kraw.x), t0);
            t0 = fmaf(qa.z, bflo(kraw.y), t0);
            t0 = fmaf(qa.w, bfhi(kraw.y), t0);
            t0 = fmaf(qw4.z, ea4.z, t0);
            float t1 = fmaf(qb.x, bflo(kraw.z), qw4.y * ea4.y);
            t1 = fmaf(qb.y, bfhi(kraw.z), t1);
            t1 = fmaf(qb.z, bflo(kraw.w), t1);
            t1 = fmaf(qb.w, bfhi(kraw.w), t1);
            t1 = fmaf(qw4.w, ea4.w, t1);
            float t = t0 + t1;
            t += __shfl_xor(t, 1, 64);
            t += __shfl_xor(t, 2, 64);
            t += __shfl_xor(t, 4, 64);
            const float score = act ? t : -3.0e38f;

            const float mn = fmaxf(m, score);
            const float p  = act ? __expf(score - mn) : 0.f;
            const float sc = __expf(m - mn);
            l = l * sc + p;
            msgA.x = fmaf(p, bflo(vraw.x), msgA.x * sc);
            msgA.y = fmaf(p, bfhi(vraw.x), msgA.y * sc);
            msgA.z = fmaf(p, bflo(vraw.y), msgA.z * sc);
            msgA.w = fmaf(p, bfhi(vraw.y), msgA.w * sc);
            msgB.x = fmaf(p, bflo(vraw.z), msgB.x * sc);
            msgB.y = fmaf(p, bfhi(vraw.z), msgB.y * sc);
            msgB.z = fmaf(p, bflo(vraw.w), msgB.z * sc);
            msgB.w = fmaf(p, bfhi(vraw.w), msgB.w * sc);
            sea.x = fmaf(p, ea4.x, sea.x * sc);
            sea.y = fmaf(p, ea4.y, sea.y * sc);
            sea.z = fmaf(p, ea4.z, sea.z * sc);
            sea.w = fmaf(p, ea4.w, sea.w * sc);
            m = mn;
        }
    }

    // merge the 8 groups over g bits (xor 8, 16, 32)
    #pragma unroll
    for (int off = 8; off <= 32; off <<= 1) {
        const float m2 = __shfl_xor(m, off, 64);
        const float l2 = __shfl_xor(l, off, 64);
        float4 a2, b2, s2;
        a2.x = __shfl_xor(msgA.x, off, 64); a2.y = __shfl_xor(msgA.y, off, 64);
        a2.z = __shfl_xor(msgA.z, off, 64); a2.w = __shfl_xor(msgA.w, off, 64);
        b2.x = __shfl_xor(msgB.x, off, 64); b2.y = __shfl_xor(msgB.y, off, 64);
        b2.z = __shfl_xor(msgB.z, off, 64); b2.w = __shfl_xor(msgB.w, off, 64);
        s2.x = __shfl_xor(sea.x, off, 64);  s2.y = __shfl_xor(sea.y, off, 64);
        s2.z = __shfl_xor(sea.z, off, 64);  s2.w = __shfl_xor(sea.w, off, 64);
        const float mn = fmaxf(m, m2);
        const float w1 = __expf(m - mn);
        const float w2 = __expf(m2 - mn);
        l = l * w1 + l2 * w2;
        msgA.x = msgA.x * w1 + a2.x * w2; msgA.y = msgA.y * w1 + a2.y * w2;
        msgA.z = msgA.z * w1 + a2.z * w2; msgA.w = msgA.w * w1 + a2.w * w2;
        msgB.x = msgB.x * w1 + b2.x * w2; msgB.y = msgB.y * w1 + b2.y * w2;
        msgB.z = msgB.z * w1 + b2.z * w2; msgB.w = msgB.w * w1 + b2.w * w2;
        sea.x = sea.x * w1 + s2.x * w2;   sea.y = sea.y * w1 + s2.y * w2;
        sea.z = sea.z * w1 + s2.z * w2;   sea.w = sea.w * w1 + s2.w * w2;
        m = mn;
    }

    // stage merged state in per-wave LDS (any one group; use g==0)
    if (g == 0) {
        *(float4*)&lsea[wave][j * 4]     = sea;
        *(float4*)&lmsg[wave][j * 8]     = msgA;
        *(float4*)&lmsg[wave][j * 8 + 4] = msgB;
    }
    // all lanes hold identical merged l after the butterfly
    const float inv = (l > 0.f) ? (1.f / l) : 0.f;

    // epilogue: lane handles output channel = lane
    float e = 0.f;
    #pragma unroll 8
    for (int j2 = 0; j2 < DEA; ++j2)
        e = fmaf(lsea[wave][j2], lw[j2 * DIM + lane], e);
    const float msgc = lmsg[wave][lane];
    const float sk = aggskip[(size_t)node * DIM + lane];
    h_out[(size_t)node * DIM + lane] = fmaxf(fmaf(msgc + e, inv, sk), 0.f);
}

// ---------------------------------------------------------------------------
// Final: out = relu(concat(h1,h2) @ skip_w + skip_b), K=128
// ---------------------------------------------------------------------------
__global__ __launch_bounds__(256) void final_kernel(
    const float* __restrict__ h1, const float* __restrict__ h2,
    const float* __restrict__ w, const float* __restrict__ b,
    float* __restrict__ out, int n_nodes)
{
    __shared__ float lw[128 * DIM];   // 32 KB
    __shared__ float lx[16][128];     // 8 KB
    const int tid = threadIdx.x;
    {
        const float4* s4 = (const float4*)w;
        float4* d4 = (float4*)lw;
        #pragma unroll
        for (int i = 0; i < 8; ++i) d4[tid + i * 256] = s4[tid + i * 256];
    }
    const int base = blockIdx.x * 16;
    {
        #pragma unroll
        for (int t = 0; t < 2; ++t) {
            const int f = tid + t * 256;
            const int r = f >> 5;
            const int cf = f & 31;
            const int n = base + r;
            float4 val = make_float4(0.f, 0.f, 0.f, 0.f);
            if (n < n_nodes) {
                if (cf < 16) val = *(const float4*)&h1[(size_t)n * DIM + cf * 4];
                else         val = *(const float4*)&h2[(size_t)n * DIM + (cf - 16) * 4];
            }
            *(float4*)&lx[r][cf * 4] = val;
        }
    }
    __syncthreads();

    const int oc = tid & 63;
    const int nl = tid >> 6;
    float acc[4] = {0, 0, 0, 0};
    #pragma unroll 8
    for (int kk = 0; kk < 128; ++kk) {
        const float wv = lw[kk * DIM + oc];
        #pragma unroll
        for (int r = 0; r < 4; ++r)
            acc[r] = fmaf(lx[nl * 4 + r][kk], wv, acc[r]);
    }
    const float bv = b[oc];
    #pragma unroll
    for (int r = 0; r < 4; ++r) {
        const int n = base + nl * 4 + r;
        if (n < n_nodes) out[(size_t)n * DIM + oc] = fmaxf(acc[r] + bv, 0.f);
    }
}

// ---------------------------------------------------------------------------
extern "C" void kernel_launch(void* const* d_in, const int* in_sizes, int n_in,
                              void* d_out, int out_size, void* d_ws, size_t ws_size,
                              hipStream_t stream)
{
    const float* x     = (const float*)d_in[0];
    const int*   ei    = (const int*)d_in[1];
    const float* eattr = (const float*)d_in[2];
    const float *q1w = (const float*)d_in[3],  *q1b = (const float*)d_in[4];
    const float *k1w = (const float*)d_in[5],  *k1b = (const float*)d_in[6];
    const float *v1w = (const float*)d_in[7],  *v1b = (const float*)d_in[8];
    const float *e1w = (const float*)d_in[9];
    const float *s1w = (const float*)d_in[10], *s1b = (const float*)d_in[11];
    const float *q2w = (const float*)d_in[12], *q2b = (const float*)d_in[13];
    const float *k2w = (const float*)d_in[14], *k2b = (const float*)d_in[15];
    const float *v2w = (const float*)d_in[16], *v2b = (const float*)d_in[17];
    const float *e2w = (const float*)d_in[18];
    const float *s2w = (const float*)d_in[19], *s2b = (const float*)d_in[20];
    const float *skw = (const float*)d_in[21], *skb = (const float*)d_in[22];

    const int N = in_sizes[0] / DIM;
    const int E = in_sizes[1] / 2;
    const int* src = ei;
    const int* dst = ei + E;

    float* ws = (float*)d_ws;
    const size_t nf = (size_t)N * DIM;
    float* q    = ws;                          // nf
    unsigned short* kvb = (unsigned short*)(q + nf);  // N*128 ushorts = nf floats
    float* agg  = q + 2 * nf;                  // nf
    float* h1   = agg + nf;                    // nf
    float* h2   = h1 + nf;                     // nf
    float* qwe  = h2 + nf;                     // 32*N
    int2* pair    = (int2*)(qwe + (size_t)DEA * N);    // E int2
    int* cursor   = (int*)(pair + E);                  // N
    int* row_ptr  = cursor + ((N + 3) & ~3);           // N+1
    const int nb  = (N + 1023) / 1024;
    int* blksum   = row_ptr + ((N + 4) & ~3);          // nb
    int* blkoff   = blksum + ((nb + 3) & ~3);          // nb
    float* wqeW1  = (float*)(blkoff + ((nb + 3) & ~3));// 2048
    float* bqe1   = wqeW1 + 64 * 32;                   // 32
    float* wqeW2  = bqe1 + 32;                         // 2048
    float* bqe2   = wqeW2 + 64 * 32;                   // 32

    const int nblk = (N + 31) / 32;
    const int eblk = (E + 255) / 256;
    const int fblk = (N + 3) / 4;
    const int finblk = (N + 15) / 16;

    // ---------------- CSR over dst + combined score weights ----------------
    hipMemsetAsync(cursor, 0, (size_t)N * sizeof(int), stream);
    hist_kernel<<<eblk, 256, 0, stream>>>(dst, cursor, E, N);
    scan_pass1_kernel<<<nb, 256, 0, stream>>>(cursor, row_ptr, blksum, N);
    scan_pass2_kernel<<<1, 64, 0, stream>>>(blksum, blkoff, row_ptr, nb, N);
    scan_pass3_kernel<<<nb, 256, 0, stream>>>(row_ptr, cursor, blkoff, N);
    scatter_kernel<<<eblk, 256, 0, stream>>>(dst, src, cursor, pair, E, N);
    wqe_prep_kernel<<<2, 256, 0, stream>>>(q1w, q1b, e1w, q2w, q2b, e2w,
                                           wqeW1, bqe1, wqeW2, bqe2);

    // ---------------- layer 1 ----------------
    node_lin_kernel<<<nblk, 256, 0, stream>>>(x, q1w, q1b, k1w, k1b, v1w, v1b,
                                              s1w, s1b, wqeW1, bqe1,
                                              q, kvb, agg, qwe, N);
    fused_edge_kernel<<<fblk, 256, 0, stream>>>(q, qwe, kvb, eattr, e1w, agg,
                                                row_ptr, pair, h1, N);

    // ---------------- layer 2 ----------------
    node_lin_kernel<<<nblk, 256, 0, stream>>>(h1, q2w, q2b, k2w, k2b, v2w, v2b,
                                              s2w, s2b, wqeW2, bqe2,
                                              q, kvb, agg, qwe, N);
    fused_edge_kernel<<<fblk, 256, 0, stream>>>(q, qwe, kvb, eattr, e2w, agg,
                                                row_ptr, pair, h2, N);

    // ---------------- final skip MLP ----------------
    final_kernel<<<finblk, 256, 0, stream>>>(h1, h2, skw, skb, (float*)d_out, N);
}